// Round 5
// baseline (1890.543 us; speedup 1.0000x reference)
//
#include <hip/hip_runtime.h>
#include <hip/hip_bf16.h>
#include <stdint.h>

// ---------------- model dims ----------------
#define V_   128
#define L_   300
#define EU_  256
#define GU_  1024    // 4*EU
#define NSTEP (299*128)   // 38272 decoder steps

// Encoder weight layout (lane-pair k-split, unchanged from R4) for wrS/wrW:
//   u = j>>1, kh = j&1; p<52 reg / p>=52 LDS at WL4_OFF.
#define WL4_OFF  26624   // uint4 offset of LDS-resident weight part (encoder layout)
#define TOL      1e-4f
#define MEMO_T   32      // max memoized trajectory length (abort build past this)
#define LREC_NONE 0xFFFFFFFFu

// Decoder weight layout (2-BLOCK split, NEW): block b owns units [b*128, b*128+128).
// 512 threads/block: ul = tix>>2 (unit 0..127), ks = tix&3 (k-quarter, 32 k-pairs each).
// Thread holds 32 uint4 = 128 f16x2 dwords = its unit's 4 gate columns over its k-quarter
// -> genuinely register-resident (fits the 256-reg/wave budget at 2 waves/SIMD).
// Weight quad (g,q) at w4[b*16384 + ((g*8+q)*512 + tix)]; component p -> kp = ks*32+q*4+p.
// Cross-block h/flag exchange each computed step via L2 + device-scope atomic counter.

typedef _Float16 h2 __attribute__((ext_vector_type(2)));

__device__ __forceinline__ float sigmoidf_(float x) { return 1.f / (1.f + __expf(-x)); }
__device__ __forceinline__ float tanhf_(float x) { return 2.f / (1.f + __expf(-2.f * x)) - 1.f; }

#if __has_builtin(__builtin_amdgcn_fdot2)
__device__ __forceinline__ float fdot2_(h2 a, h2 b, float c) { return __builtin_amdgcn_fdot2(a, b, c, false); }
#else
__device__ __forceinline__ float fdot2_(h2 a, h2 b, float c) {
    return c + (float)a.x * (float)b.x + (float)a.y * (float)b.y;
}
#endif

__device__ __forceinline__ h2 bch2(uint32_t u) {
    union { uint32_t u; h2 h; } x; x.u = u; return x.h;
}

__device__ __forceinline__ unsigned short bf16bits_(float f) {
    union { __hip_bfloat16 b; unsigned short s; } x;
    x.b = __float2bfloat16(f);
    return x.s;
}

// ---------------- encoder macros (lane-pair layout, unchanged) ----------------
#define P13(M) M(0) M(1) M(2) M(3) M(4) M(5) M(6) M(7) M(8) M(9) M(10) M(11) M(12)

#define DECLW4(t) uint4 Wa##t, Wb##t, Wc##t, Wd##t;
#define LOADW4(t) Wa##t = w4[(4*(t)+0)*512 + j]; Wb##t = w4[(4*(t)+1)*512 + j]; \
                  Wc##t = w4[(4*(t)+2)*512 + j]; Wd##t = w4[(4*(t)+3)*512 + j];

#define DOTT(t) { uint4 hv = hp4[hb + (t)]; \
    a0 = fdot2_(bch2(Wa##t.x), bch2(hv.x), a0); a1 = fdot2_(bch2(Wa##t.y), bch2(hv.x), a1); \
    a2 = fdot2_(bch2(Wa##t.z), bch2(hv.x), a2); a3 = fdot2_(bch2(Wa##t.w), bch2(hv.x), a3); \
    b0 = fdot2_(bch2(Wb##t.x), bch2(hv.y), b0); b1 = fdot2_(bch2(Wb##t.y), bch2(hv.y), b1); \
    b2 = fdot2_(bch2(Wb##t.z), bch2(hv.y), b2); b3 = fdot2_(bch2(Wb##t.w), bch2(hv.y), b3); \
    a0 = fdot2_(bch2(Wc##t.x), bch2(hv.z), a0); a1 = fdot2_(bch2(Wc##t.y), bch2(hv.z), a1); \
    a2 = fdot2_(bch2(Wc##t.z), bch2(hv.z), a2); a3 = fdot2_(bch2(Wc##t.w), bch2(hv.z), a3); \
    b0 = fdot2_(bch2(Wd##t.x), bch2(hv.w), b0); b1 = fdot2_(bch2(Wd##t.y), bch2(hv.w), b1); \
    b2 = fdot2_(bch2(Wd##t.z), bch2(hv.w), b2); b3 = fdot2_(bch2(Wd##t.w), bch2(hv.w), b3); }

#define DOTL(tt) { uint4 hv = hp4[hb + 13 + (tt)]; \
    uint4 w0 = wl_s[((tt)*4+0)*512 + j]; uint4 w1 = wl_s[((tt)*4+1)*512 + j]; \
    uint4 w2 = wl_s[((tt)*4+2)*512 + j]; uint4 w3 = wl_s[((tt)*4+3)*512 + j]; \
    a0 = fdot2_(bch2(w0.x), bch2(hv.x), a0); a1 = fdot2_(bch2(w0.y), bch2(hv.x), a1); \
    a2 = fdot2_(bch2(w0.z), bch2(hv.x), a2); a3 = fdot2_(bch2(w0.w), bch2(hv.x), a3); \
    b0 = fdot2_(bch2(w1.x), bch2(hv.y), b0); b1 = fdot2_(bch2(w1.y), bch2(hv.y), b1); \
    b2 = fdot2_(bch2(w1.z), bch2(hv.y), b2); b3 = fdot2_(bch2(w1.w), bch2(hv.y), b3); \
    a0 = fdot2_(bch2(w2.x), bch2(hv.z), a0); a1 = fdot2_(bch2(w2.y), bch2(hv.z), a1); \
    a2 = fdot2_(bch2(w2.z), bch2(hv.z), a2); a3 = fdot2_(bch2(w2.w), bch2(hv.z), a3); \
    b0 = fdot2_(bch2(w3.x), bch2(hv.w), b0); b1 = fdot2_(bch2(w3.y), bch2(hv.w), b1); \
    b2 = fdot2_(bch2(w3.z), bch2(hv.w), b2); b3 = fdot2_(bch2(w3.w), bch2(hv.w), b3); }

#define DOTS_ALL4() \
    float a0 = 0.f, a1 = 0.f, a2 = 0.f, a3 = 0.f; \
    float b0 = 0.f, b1 = 0.f, b2 = 0.f, b3 = 0.f; \
    { const uint4* hp4 = (const uint4*)hp; const int hb = kh * 16; \
      P13(DOTT) \
      DOTL(0) DOTL(1) DOTL(2) }

// ---------------- decoder macros (2-block layout) ----------------
#define WQ(M) M(0,0) M(0,1) M(0,2) M(0,3) M(0,4) M(0,5) M(0,6) M(0,7) \
              M(1,0) M(1,1) M(1,2) M(1,3) M(1,4) M(1,5) M(1,6) M(1,7) \
              M(2,0) M(2,1) M(2,2) M(2,3) M(2,4) M(2,5) M(2,6) M(2,7) \
              M(3,0) M(3,1) M(3,2) M(3,3) M(3,4) M(3,5) M(3,6) M(3,7)
#define DECLQ(g,q) uint4 W##g##_##q;
#define LOADQ(g,q) W##g##_##q = w4[((g)*8+(q))*512 + tix];
#define DOTQ1(g,q,hv,A,B) \
    A = fdot2_(bch2(W##g##_##q.x), bch2(hv.x), A); B = fdot2_(bch2(W##g##_##q.y), bch2(hv.y), B); \
    A = fdot2_(bch2(W##g##_##q.z), bch2(hv.z), A); B = fdot2_(bch2(W##g##_##q.w), bch2(hv.w), B);
#define DOT8(g,A,B) DOTQ1(g,0,hv0,A,B) DOTQ1(g,1,hv1,A,B) DOTQ1(g,2,hv2,A,B) DOTQ1(g,3,hv3,A,B) \
                    DOTQ1(g,4,hv4,A,B) DOTQ1(g,5,hv5,A,B) DOTQ1(g,6,hv6,A,B) DOTQ1(g,7,hv7,A,B)

// ---------------- weight repack: encoder layout (m<2), decoder 2-block layout (m==2) ------
__global__ void prep_wh_kernel(const float* __restrict__ WhS, const float* __restrict__ WhW,
                               const float* __restrict__ WhD, uint32_t* __restrict__ wS,
                               uint32_t* __restrict__ wW, uint32_t* __restrict__ wD) {
    int bi = blockIdx.x;           // 1536 blocks = 3 matrices x 512
    int m = bi >> 9;
    const float* Wh = (m == 0) ? WhS : (m == 1) ? WhW : WhD;
    uint32_t* wbuf = (m == 0) ? wS : (m == 1) ? wW : wD;
    int idx = (bi & 511) * 256 + threadIdx.x;   // 131072 dwords
    int kp = idx >> 10, col = idx & 1023;
    union { _Float16 f[2]; uint32_t u; } pk;
    pk.f[0] = (_Float16)Wh[(2 * kp) * 1024 + col];
    pk.f[1] = (_Float16)Wh[(2 * kp + 1) * 1024 + col];
    int g = col >> 8, u = col & 255;
    if (m < 2) {
        int kh = kp >> 6, pp = kp & 63;
        int j = (u << 1) | kh;
        int dst = (pp < 52) ? ((pp * 512 + j) * 4 + g)
                            : (WL4_OFF * 4 + ((pp - 52) * 512 + j) * 4 + g);
        wbuf[dst] = pk.u;
    } else {
        int b = u >> 7, ul = u & 127;
        int ks = kp >> 5, qq = (kp >> 2) & 7, p = kp & 3;
        int t = ul * 4 + ks;
        wbuf[b * 65536 + (((g * 8 + qq) * 512) + t) * 4 + p] = pk.u;
    }
}

// ---------------- fused encoder LSTMs: block 0 = stft (T=14), block 1 = wave (T=62) -------
__global__ __launch_bounds__(512, 2) __attribute__((amdgpu_waves_per_eu(2, 2)))
void lstm_enc5_kernel(const uint32_t* __restrict__ wS, const float* __restrict__ xpS,
                      float* __restrict__ shp, float* __restrict__ scp,
                      const uint32_t* __restrict__ wW, const float* __restrict__ xpW,
                      float* __restrict__ whp, float* __restrict__ wcp) {
    __shared__ uint4 wl_s[12 * 512];               // 96 KiB
    __shared__ __align__(16) uint32_t h_pk[2][128];
    const uint32_t* wbuf = blockIdx.x ? wW : wS;
    const float* xp = blockIdx.x ? xpW : xpS;
    float* h_out = blockIdx.x ? whp : shp;
    float* c_out = blockIdx.x ? wcp : scp;
    int T = blockIdx.x ? 62 : 14;
    int j = threadIdx.x;
    int u = j >> 1, kh = j & 1;
    const uint4* w4 = (const uint4*)wbuf;
    P13(DECLW4)
    P13(LOADW4)
    for (int i = j; i < 6144; i += 512) wl_s[i] = w4[WL4_OFF + i];
    if (j < 128) h_pk[0][j] = 0;
    float c = 0.f, h = 0.f;
    __syncthreads();
    int cur = 0;
    for (int t = 0; t < T; ++t) {
        const uint32_t* hp = &h_pk[cur][0];
        DOTS_ALL4()
        float s0 = a0 + b0, s1 = a1 + b1, s2 = a2 + b2, s3 = a3 + b3;
        const float* xr = xp + t * 1024;
        float zi = s0 + __shfl_xor(s0, 1) + xr[u];
        float zf = s1 + __shfl_xor(s1, 1) + xr[256 + u];
        float zg = s2 + __shfl_xor(s2, 1) + xr[512 + u];
        float zo = s3 + __shfl_xor(s3, 1) + xr[768 + u];
        c = sigmoidf_(zf) * c + sigmoidf_(zi) * tanhf_(zg);
        h = sigmoidf_(zo) * tanhf_(c);
        if (!kh) ((_Float16*)&h_pk[cur ^ 1][0])[u] = (_Float16)h;
        __syncthreads();
        cur ^= 1;
    }
    if (!kh) { h_out[u] = h; c_out[u] = c; }
}

// ---------------- decoder: 2-CU split, register-resident weights, cross-CU h exchange -----
__global__ __launch_bounds__(512, 2) __attribute__((amdgpu_waves_per_eu(2, 2)))
void lstm_dec10_kernel(const uint32_t* __restrict__ wbuf, const float* __restrict__ a01,
                       const int* __restrict__ tok, const float* __restrict__ h0,
                       const float* __restrict__ c0, __hip_bfloat16* __restrict__ uniq,
                       uint32_t* __restrict__ rid, uint32_t* __restrict__ lrec,
                       int* __restrict__ gpar, uint32_t* __restrict__ xg,
                       uint32_t* __restrict__ syncc) {
    __shared__ __align__(16) uint32_t h_pk[2][128];
    __shared__ int flagv[8];
    __shared__ int statv;
    __shared__ uint32_t memo_st[MEMO_T * 128];   // own units: f16 h | f16 c
    __shared__ uint32_t memo_oh[MEMO_T * 64];    // partner block's packed h dwords
    __shared__ int tok_s[304];
    const int tix = threadIdx.x;
    const int blk = blockIdx.x;              // 0 or 1
    const int ul = tix >> 2, ks = tix & 3;
    const int ug = blk * 128 + ul;           // global unit
    const uint4* w4 = (const uint4*)wbuf + blk * 16384;
    WQ(DECLQ)
    WQ(LOADQ)
    for (int i = tix; i < 299; i += 512) tok_s[i] = tok[i];
    float a0i = a01[ug], a0f = a01[256 + ug], a0g = a01[512 + ug], a0o = a01[768 + ug];
    float a1i = a01[1024 + ug], a1f = a01[1280 + ug], a1g = a01[1536 + ug], a1o = a01[1792 + ug];
    float h = h0[ug], c = c0[ug];
    if (tix < 128) {
        union { _Float16 f[2]; uint32_t u; } pk;
        pk.f[0] = (_Float16)h0[2 * tix];
        pk.f[1] = (_Float16)h0[2 * tix + 1];
        h_pk[0][tix] = pk.u;
    }
    __syncthreads();
    int cur = 0;
    bool prev_a0 = false, stat = false;
    bool memo_valid = false, building = false;
    int bidx = 0, memo_len = 0, mid0 = 0;
    int uc = 0, step = 0, esteps = 0;
#pragma unroll 1
    for (int l = 0; l < 299; ++l) {
        int tk = tok_s[l];
        // canonical l: full replay guaranteed, ends at the fixed point -> skip entirely
        if (stat && memo_valid && tk <= 128 - memo_len) {
            if (blk == 0 && tix == 0) lrec[l] = (uint32_t)(uc - 1);
            step += 128;
            prev_a0 = true;
            continue;
        }
        if (blk == 0 && tix == 0) lrec[l] = LREC_NONE;
        int v = 0;
        while (v < 128) {
            if (stat && v != tk) {
                int nxt = (v < tk) ? tk : 128;
                int cnt = nxt - v;
                if (blk == 0 && tix < cnt) rid[step + tix] = (uint32_t)(uc - 1);
                step += cnt;
                v = nxt;
                continue;
            }
            if (v == tk && stat && memo_valid) {
                // replay memoized perturbation trajectory: ids + local full-state restore
                int M = (memo_len < 128 - v) ? memo_len : (128 - v);
                if (blk == 0 && tix < M) rid[step + tix] = (uint32_t)(mid0 + tix);
                {
                    union { uint32_t w; _Float16 f[2]; } s;
                    s.w = memo_st[(M - 1) * 128 + ul];
                    h = (float)s.f[0];
                    c = (float)s.f[1];
                }
                if (tix < 64) {
                    uint32_t m0 = memo_st[(M - 1) * 128 + 2 * tix];
                    uint32_t m1 = memo_st[(M - 1) * 128 + 2 * tix + 1];
                    h_pk[cur][blk * 64 + tix] = (m0 & 0xffffu) | ((m1 & 0xffffu) << 16);
                    h_pk[cur][(1 - blk) * 64 + tix] = memo_oh[(M - 1) * 64 + tix];
                }
                step += M;
                v += M;
                if (M == memo_len) { stat = true; prev_a0 = true; }
                else { stat = false; prev_a0 = (M > 1); }
                __syncthreads();
                continue;
            }
            // normal computed step (records memo during build); cross-CU exchange at end
            bool isa1 = (v == tk);
            if (isa1 && stat && !memo_valid && !building) { building = true; bidx = 0; mid0 = uc; }
            int par = esteps & 1;
            {
                const uint4* hp4 = (const uint4*)&h_pk[cur][0];
                const int hb = ks * 8;
                uint4 hv0 = hp4[hb + 0], hv1 = hp4[hb + 1], hv2 = hp4[hb + 2], hv3 = hp4[hb + 3];
                uint4 hv4 = hp4[hb + 4], hv5 = hp4[hb + 5], hv6 = hp4[hb + 6], hv7 = hp4[hb + 7];
                float iA = 0.f, iB = 0.f, fA = 0.f, fB = 0.f;
                float gA = 0.f, gB = 0.f, oA = 0.f, oB = 0.f;
                DOT8(0, iA, iB) DOT8(1, fA, fB) DOT8(2, gA, gB) DOT8(3, oA, oB)
                float si = iA + iB, sf = fA + fB, sg = gA + gB, so = oA + oB;
                si += __shfl_xor(si, 1); sf += __shfl_xor(sf, 1);
                sg += __shfl_xor(sg, 1); so += __shfl_xor(so, 1);
                si += __shfl_xor(si, 2); sf += __shfl_xor(sf, 2);
                sg += __shfl_xor(sg, 2); so += __shfl_xor(so, 2);
                float zi = si + (isa1 ? a1i : a0i);
                float zf = sf + (isa1 ? a1f : a0f);
                float zg = sg + (isa1 ? a1g : a0g);
                float zo = so + (isa1 ? a1o : a0o);
                float cn = sigmoidf_(zf) * c + sigmoidf_(zi) * tanhf_(zg);
                float hn = sigmoidf_(zo) * tanhf_(cn);
                bool ok = (fabsf(hn - h) <= TOL) && (fabsf(cn - c) <= TOL) && !isa1 && prev_a0;
                unsigned long long bal = __ballot(ok ? 1 : 0);
                if ((tix & 63) == 0) flagv[tix >> 6] = (bal == ~0ull) ? 1 : 0;
                h = hn;
                c = cn;
                if (ks == 0) ((unsigned short*)uniq)[(size_t)uc * 256 + ug] = bf16bits_(hn);
                // pack own pair (units 2m,2m+1) for h_pk and the exchange payload
                float hnp = __shfl(hn, ((tix & 63) + 4) & 63);
                if ((tix & 7) == 0) {
                    union { _Float16 f[2]; uint32_t u; } pk;
                    pk.f[0] = (_Float16)hn;
                    pk.f[1] = (_Float16)hnp;
                    h_pk[cur ^ 1][blk * 64 + (ul >> 1)] = pk.u;
                    xg[(par * 2 + blk) * 128 + (ul >> 1)] = pk.u;
                }
                if (ks == 0 && building) {
                    union { _Float16 f[2]; uint32_t u; } s;
                    s.f[0] = (_Float16)hn;
                    s.f[1] = (_Float16)cn;
                    memo_st[bidx * 128 + ul] = s.u;
                }
                if (blk == 0 && tix == 0) rid[step] = (uint32_t)uc;
            }
            __syncthreads();   // B1: flagv + payload-h written block-wide
            if (tix == 0) {
                int myok = flagv[0] && flagv[1] && flagv[2] && flagv[3] &&
                           flagv[4] && flagv[5] && flagv[6] && flagv[7];
                xg[(par * 2 + blk) * 128 + 64] = (uint32_t)myok;
                __hip_atomic_fetch_add(syncc, 1u, __ATOMIC_RELEASE, __HIP_MEMORY_SCOPE_AGENT);
                uint32_t tgt = 2u * (uint32_t)(esteps + 1);
                int it = 0;
                while (__hip_atomic_load(syncc, __ATOMIC_ACQUIRE, __HIP_MEMORY_SCOPE_AGENT) < tgt
                       && it < (1 << 20)) ++it;
                uint32_t otherok = xg[(par * 2 + (1 - blk)) * 128 + 64];
                statv = (myok && otherok) ? 1 : 0;
            }
            __syncthreads();   // B2: acquire + statv visible
            if (tix < 64) {
                uint32_t od = xg[(par * 2 + (1 - blk)) * 128 + tix];
                h_pk[cur ^ 1][(1 - blk) * 64 + tix] = od;
                if (building) memo_oh[bidx * 64 + tix] = od;
            }
            __syncthreads();   // B3: h_pk complete for next step
            stat = statv != 0;
            cur ^= 1;
            prev_a0 = !isa1;
            ++step;
            ++v;
            ++uc;
            ++esteps;
            if (building) {
                if (stat) { memo_len = bidx + 1; memo_valid = true; building = false; }
                else if (bidx + 1 >= MEMO_T) building = false;  // abort: too long
                else ++bidx;
            }
        }
        building = false;  // abort any build crossing an l boundary
    }
    if (blk == 0 && tix == 0) {
        gpar[0] = uc;                               // unique-row count
        gpar[1] = mid0;                             // memo base row id
        gpar[2] = memo_valid ? memo_len : 0;        // memo length (0 = no memo)
    }
}

// ---------------- tok extraction ----------------
__global__ void tok_kernel(const float* __restrict__ din, int* __restrict__ tok) {
    int l = blockIdx.x * 64 + threadIdx.x;
    if (l >= 299) return;
    int t = 0;
    for (int v = 0; v < 128; ++v)
        if (din[l * 128 + v] > 0.5f) t = v;
    tok[l] = t;
}

// ---------------- STFT conv1 (3x3x1->256) + relu + 2x2 maxpool ----------------
__global__ void stft_conv1_kernel(const float* __restrict__ in, const float* __restrict__ w,
                                  const float* __restrict__ b, float* __restrict__ out) {
    int c = threadIdx.x;
    int blk = blockIdx.x;
    int pw = blk % 255, ph = blk / 255;
    int h0 = 2 * ph, w0 = 2 * pw;
    float pin[4][4];
#pragma unroll
    for (int r = 0; r < 4; ++r)
#pragma unroll
        for (int s = 0; s < 4; ++s) pin[r][s] = in[(h0 + r) * 513 + (w0 + s)];
    float acc[2][2] = {};
#pragma unroll
    for (int dh = 0; dh < 3; ++dh)
#pragma unroll
        for (int dw = 0; dw < 3; ++dw) {
            float wv = w[(dh * 3 + dw) * 256 + c];
            acc[0][0] += pin[dh][dw] * wv;
            acc[0][1] += pin[dh][dw + 1] * wv;
            acc[1][0] += pin[dh + 1][dw] * wv;
            acc[1][1] += pin[dh + 1][dw + 1] * wv;
        }
    float m = fmaxf(fmaxf(acc[0][0], acc[0][1]), fmaxf(acc[1][0], acc[1][1]));
    out[(ph * 255 + pw) * 256 + c] = fmaxf(m + b[c], 0.f);
}

// ---------------- STFT conv2 (3x3x256->256) + relu + 2x2 maxpool, float4 LDS reads -------
__global__ void stft_conv2_kernel(const float* __restrict__ P1, const float* __restrict__ w,
                                  const float* __restrict__ b, float* __restrict__ out) {
    __shared__ __align__(16) float patch[4 * 8 * 256];
    int c = threadIdx.x;
    int blk = blockIdx.x;
    int pwg = blk % 42, ph = blk / 42;
    int pw0 = pwg * 3;
    int r0 = 2 * ph, c0 = 2 * pw0;
    for (int i = c; i < 4 * 8 * 256; i += 256) {
        int ci = i & 255;
        int t = i >> 8;
        int cc = t & 7, r = t >> 3;
        patch[i] = P1[((r0 + r) * 255 + (c0 + cc)) * 256 + ci];
    }
    __syncthreads();
    const float4* patch4 = (const float4*)patch;
    float acc[3][2][2] = {};
    for (int dh = 0; dh < 3; ++dh) {
        for (int ci = 0; ci < 256; ci += 4) {
            float4 p0[8], p1[8];
#pragma unroll
            for (int x = 0; x < 8; ++x) {
                p0[x] = patch4[((dh * 8 + x) * 256 + ci) >> 2];
                p1[x] = patch4[(((dh + 1) * 8 + x) * 256 + ci) >> 2];
            }
#pragma unroll
            for (int r = 0; r < 4; ++r) {
#pragma unroll
                for (int dw = 0; dw < 3; ++dw) {
                    float wv = w[((dh * 3 + dw) * 256 + ci + r) * 256 + c];
#pragma unroll
                    for (int o = 0; o < 3; ++o)
#pragma unroll
                        for (int s = 0; s < 2; ++s) {
                            int x = 2 * o + s + dw;
                            acc[o][0][s] += ((const float*)&p0[x])[r] * wv;
                            acc[o][1][s] += ((const float*)&p1[x])[r] * wv;
                        }
                }
            }
        }
    }
    float bv = b[c];
#pragma unroll
    for (int o = 0; o < 3; ++o) {
        float m = fmaxf(fmaxf(acc[o][0][0], acc[o][0][1]), fmaxf(acc[o][1][0], acc[o][1][1]));
        out[(ph * 126 + (pw0 + o)) * 256 + c] = fmaxf(m + bv, 0.f);
    }
}

// ---------------- STFT input projection: X[14,32256] @ Wi[32256,1024], split-K ------------
__global__ void xprojS_partial_kernel(const float* __restrict__ X, const float* __restrict__ Wi,
                                      float* __restrict__ part) {
    __shared__ __align__(16) float xbuf[14 * 504];
    int tid = threadIdx.x;
    int kc = blockIdx.x & 63;
    int cb = blockIdx.x >> 6;
    int col = cb * 256 + tid;
    int k0 = kc * 504;
    for (int i = tid; i < 14 * 504; i += 256) {
        int t = i / 504;
        int kk = i - t * 504;
        xbuf[i] = X[t * 32256 + k0 + kk];
    }
    __syncthreads();
    const float4* xb4 = (const float4*)xbuf;
    float acc[14] = {};
    for (int kk = 0; kk < 504; kk += 4) {
        float wv0 = Wi[(size_t)(k0 + kk) * 1024 + col];
        float wv1 = Wi[(size_t)(k0 + kk + 1) * 1024 + col];
        float wv2 = Wi[(size_t)(k0 + kk + 2) * 1024 + col];
        float wv3 = Wi[(size_t)(k0 + kk + 3) * 1024 + col];
#pragma unroll
        for (int t = 0; t < 14; ++t) {
            float4 xv = xb4[(t * 504 + kk) >> 2];
            acc[t] += xv.x * wv0 + xv.y * wv1 + xv.z * wv2 + xv.w * wv3;
        }
    }
#pragma unroll
    for (int t = 0; t < 14; ++t) part[(kc * 14 + t) * 1024 + col] = acc[t];
}

__global__ void xprojS_reduce_kernel(const float* __restrict__ part, const float* __restrict__ bias,
                                     float* __restrict__ xp) {
    int idx = blockIdx.x * 256 + threadIdx.x;  // < 14*1024
    int t = idx >> 10, col = idx & 1023;
    float s = bias[col];
    for (int kc = 0; kc < 64; ++kc) s += part[(kc * 14 + t) * 1024 + col];
    xp[idx] = s;
}

// ---------------- wave conv1 (k=3, 1024->256) + relu + pool2, float4 LDS reads ------------
__global__ void wave_conv1_kernel(const float* __restrict__ in, const float* __restrict__ w,
                                  const float* __restrict__ b, float* __restrict__ out) {
    __shared__ __align__(16) float patch[4 * 1024];
    int c = threadIdx.x, t = blockIdx.x;
    for (int i = c; i < 4 * 1024; i += 256) patch[i] = in[(2 * t) * 1024 + i];
    __syncthreads();
    const float4* patch4 = (const float4*)patch;
    float acc0 = 0.f, acc1 = 0.f;
    for (int dt = 0; dt < 3; ++dt)
        for (int ci = 0; ci < 1024; ci += 4) {
            float4 q0 = patch4[(dt * 1024 + ci) >> 2];
            float4 q1 = patch4[((dt + 1) * 1024 + ci) >> 2];
#pragma unroll
            for (int r = 0; r < 4; ++r) {
                float wv = w[(dt * 1024 + ci + r) * 256 + c];
                acc0 += ((const float*)&q0)[r] * wv;
                acc1 += ((const float*)&q1)[r] * wv;
            }
        }
    out[t * 256 + c] = fmaxf(fmaxf(acc0, acc1) + b[c], 0.f);
}

// ---------------- wave conv2 (k=3, 256->256) + relu + pool2, float4 LDS reads -------------
__global__ void wave_conv2_kernel(const float* __restrict__ in, const float* __restrict__ w,
                                  const float* __restrict__ b, float* __restrict__ out) {
    __shared__ __align__(16) float patch[4 * 256];
    int c = threadIdx.x, t = blockIdx.x;
    for (int i = c; i < 4 * 256; i += 256) patch[i] = in[(2 * t) * 256 + i];
    __syncthreads();
    const float4* patch4 = (const float4*)patch;
    float acc0 = 0.f, acc1 = 0.f;
    for (int dt = 0; dt < 3; ++dt)
        for (int ci = 0; ci < 256; ci += 4) {
            float4 q0 = patch4[(dt * 256 + ci) >> 2];
            float4 q1 = patch4[((dt + 1) * 256 + ci) >> 2];
#pragma unroll
            for (int r = 0; r < 4; ++r) {
                float wv = w[(dt * 256 + ci + r) * 256 + c];
                acc0 += ((const float*)&q0)[r] * wv;
                acc1 += ((const float*)&q1)[r] * wv;
            }
        }
    out[t * 256 + c] = fmaxf(fmaxf(acc0, acc1) + b[c], 0.f);
}

// ---------------- wave input projection X[62,256] @ Wi[256,1024] + b ----------------
__global__ void xprojW_kernel(const float* __restrict__ X, const float* __restrict__ Wi,
                              const float* __restrict__ bias, float* __restrict__ xp) {
    int idx = blockIdx.x * 256 + threadIdx.x;  // 62*1024
    int t = idx >> 10, col = idx & 1023;
    float s = bias[col];
    for (int k = 0; k < 256; ++k) s += X[t * 256 + k] * Wi[k * 1024 + col];
    xp[idx] = s;
}

// ---------------- state reducers ----------------
__global__ void reduce_state_kernel(const float* __restrict__ sh, const float* __restrict__ sc,
                                    const float* __restrict__ wh, const float* __restrict__ wc,
                                    const float* __restrict__ rhw, const float* __restrict__ rhb,
                                    const float* __restrict__ rcw, const float* __restrict__ rcb,
                                    float* __restrict__ h0, float* __restrict__ c0) {
    int m = threadIdx.x;  // 256
    float ah = rhb[m], ac = rcb[m];
    for (int k = 0; k < 256; ++k) {
        ah += sh[k] * rhw[k * 256 + m];
        ac += sc[k] * rcw[k * 256 + m];
    }
    for (int k = 0; k < 256; ++k) {
        ah += wh[k] * rhw[(256 + k) * 256 + m];
        ac += wc[k] * rcw[(256 + k) * 256 + m];
    }
    h0[m] = ah;
    c0[m] = ac;
}

// ---------------- a0/a1 = emb[s] @ d_Wi + d_b ; also resets the decoder sync counter ------
__global__ void a01_kernel(const float* __restrict__ emb, const float* __restrict__ Wi,
                           const float* __restrict__ bias, float* __restrict__ a01,
                           uint32_t* __restrict__ syncc) {
    if (blockIdx.x == 0 && threadIdx.x == 0)
        __hip_atomic_store(syncc, 0u, __ATOMIC_RELAXED, __HIP_MEMORY_SCOPE_AGENT);
    int idx = blockIdx.x * 256 + threadIdx.x;  // 2048
    int s = idx >> 10, j = idx & 1023;
    float acc = bias[j];
    for (int k = 0; k < 256; ++k) acc += emb[s * 256 + k] * Wi[k * 1024 + j];
    a01[idx] = acc;
}

// ---------------- projection + softmax over UNIQUE rows: 4 rows/block ----------------
__global__ __launch_bounds__(256) void proj_softmax_kernel(const __hip_bfloat16* __restrict__ uniq,
                                                           const float* __restrict__ Wo,
                                                           const float* __restrict__ bo,
                                                           const int* __restrict__ gpar,
                                                           float* __restrict__ ptab) {
    __shared__ float hrows[4][256];
    __shared__ float llds[4][128];
    int tid = threadIdx.x;
    int rbase = blockIdx.x * 4;
    int U = gpar[0];
    if (rbase >= U) return;   // early-exit: only ~uc/4 blocks do work
    for (int i = tid; i < 1024; i += 256)
        hrows[i >> 8][i & 255] = __bfloat162float(uniq[(size_t)rbase * 256 + i]);
    __syncthreads();
    int w = tid & 127, half = tid >> 7;
    int k0 = half * 128;
    float acc[4] = {};
    for (int k = 0; k < 128; ++k) {
        float wv = Wo[(k0 + k) * 128 + w];
#pragma unroll
        for (int r = 0; r < 4; ++r) acc[r] += hrows[r][k0 + k] * wv;
    }
    if (half == 0) {
#pragma unroll
        for (int r = 0; r < 4; ++r) llds[r][w] = acc[r] + bo[w];
    }
    __syncthreads();
    if (half == 1) {
#pragma unroll
        for (int r = 0; r < 4; ++r) llds[r][w] += acc[r];
    }
    __syncthreads();
    int rr = tid >> 6, lane = tid & 63;
    float x0 = llds[rr][lane], x1 = llds[rr][lane + 64];
    float mx = fmaxf(x0, x1);
    for (int off = 32; off > 0; off >>= 1) mx = fmaxf(mx, __shfl_xor(mx, off));
    float e0 = __expf(x0 - mx), e1 = __expf(x1 - mx);
    float sm = e0 + e1;
    for (int off = 32; off > 0; off >>= 1) sm += __shfl_xor(sm, off);
    float inv = 1.f / sm;
    int row = rbase + rr;
    float* op = ptab + (size_t)row * 128;
    op[lane] = e0 * inv;
    op[lane + 64] = e1 * inv;
}

// ---------------- scatter: out[v,l,:] = ptab[id(l,v)]  (l==299 -> 0) ----------------
__global__ void scatter_out_kernel(const float* __restrict__ ptab,
                                   const uint32_t* __restrict__ rid,
                                   const uint32_t* __restrict__ lrec,
                                   const int* __restrict__ gpar,
                                   const int* __restrict__ tok,
                                   float* __restrict__ out) {
    int idx = blockIdx.x * 256 + threadIdx.x;  // 300*128*128 = 4915200
    int w = idx & 127;
    int step = idx >> 7;       // l*128 + v, l in [0,300)
    int l = step >> 7;
    int v = step & 127;
    float val = 0.f;
    if (l < 299) {
        uint32_t fr = lrec[l];
        uint32_t id;
        if (fr == LREC_NONE) {
            id = rid[step];
        } else {
            int tk = tok[l];
            int d = v - tk;
            int mlen = gpar[2];
            id = (d >= 0 && d < mlen) ? (uint32_t)(gpar[1] + d) : fr;
        }
        val = ptab[(size_t)id * 128 + w];
    }
    out[((size_t)v * 300 + l) * 128 + w] = val;
}

extern "C" void kernel_launch(void* const* d_in, const int* in_sizes, int n_in, void* d_out,
                              int out_size, void* d_ws, size_t ws_size, hipStream_t stream) {
    const float* stft = (const float*)d_in[0];
    const float* wave = (const float*)d_in[1];
    const float* din = (const float*)d_in[2];
    const float* s_cw1 = (const float*)d_in[3];
    const float* s_cb1 = (const float*)d_in[4];
    const float* s_cw2 = (const float*)d_in[5];
    const float* s_cb2 = (const float*)d_in[6];
    const float* s_Wi = (const float*)d_in[7];
    const float* s_Wh = (const float*)d_in[8];
    const float* s_b = (const float*)d_in[9];
    const float* w_cw1 = (const float*)d_in[10];
    const float* w_cb1 = (const float*)d_in[11];
    const float* w_cw2 = (const float*)d_in[12];
    const float* w_cb2 = (const float*)d_in[13];
    const float* w_Wi = (const float*)d_in[14];
    const float* w_Wh = (const float*)d_in[15];
    const float* w_b = (const float*)d_in[16];
    const float* rh_w = (const float*)d_in[17];
    const float* rh_b = (const float*)d_in[18];
    const float* rc_w = (const float*)d_in[19];
    const float* rc_b = (const float*)d_in[20];
    const float* emb = (const float*)d_in[21];
    const float* d_Wi = (const float*)d_in[22];
    const float* d_Wh = (const float*)d_in[23];
    const float* d_b = (const float*)d_in[24];
    const float* out_w = (const float*)d_in[25];
    const float* out_b = (const float*)d_in[26];
    float* out = (float*)d_out;
    float* ws = (float*)d_ws;

    // workspace layout (float offsets)
    const size_t off_P1s = 0;                         // 31*255*256 = 2023680 (reused for packed weights)
    const size_t off_P2s = off_P1s + 2023680;         // 14*126*256 = 451584
    const size_t off_partS = off_P2s + 451584;        // 64*14*1024 = 917504
    const size_t off_P1w = off_partS + 917504;        // 127*256 = 32512
    const size_t off_P2w = off_P1w + 32512;           // 62*256 = 15872
    const size_t off_xprojS = off_P2w + 15872;        // 14*1024
    const size_t off_xprojW = off_xprojS + 14336;     // 62*1024
    const size_t off_sh = off_xprojW + 63488;         // 4*256 states
    const size_t off_sc = off_sh + 256;
    const size_t off_wh = off_sc + 256;
    const size_t off_wc = off_wh + 256;
    const size_t off_h0 = off_wc + 256;
    const size_t off_c0 = off_h0 + 256;
    const size_t off_a01 = off_c0 + 256;              // 2048
    const size_t off_tok = off_a01 + 2048;            // 299 ints (512 slots)
    const size_t off_uniq = off_tok + 512;            // bf16 region: 38272*256 bf16 = 4898816 floats
    const size_t off_rid = off_uniq + 4898816;        // 38272 u32
    const size_t off_lrec = off_rid + 38272;          // 300 u32 (padded 320)
    const size_t off_gpar = off_lrec + 320;           // 3 ints (padded 64)
    const size_t off_xg = off_gpar + 64;              // 512 u32 exchange payload
    const size_t off_sync = off_xg + 512;             // 64 u32 sync counter
    const size_t off_ptab = off_sync + 64;            // 38272*128 floats (worst-case unique rows)
    __hip_bfloat16* h_uniq = (__hip_bfloat16*)(ws + off_uniq);
    uint32_t* rid = (uint32_t*)(ws + off_rid);
    uint32_t* lrec = (uint32_t*)(ws + off_lrec);
    int* gpar = (int*)(ws + off_gpar);
    uint32_t* xg = (uint32_t*)(ws + off_xg);
    uint32_t* syncc = (uint32_t*)(ws + off_sync);
    float* ptab = ws + off_ptab;
    int* tok = (int*)(ws + off_tok);
    // packed f16 weights overlay the P1s region (free after stft_conv2): 3 x 131072 dwords
    uint32_t* wrS = (uint32_t*)(ws + off_P1s);
    uint32_t* wrW = wrS + 131072;
    uint32_t* wrD = wrW + 131072;

    tok_kernel<<<5, 64, 0, stream>>>(din, tok);

    // STFT conv pipeline (P1s in use until stft_conv2 completes)
    stft_conv1_kernel<<<31 * 255, 256, 0, stream>>>(stft, s_cw1, s_cb1, ws + off_P1s);
    stft_conv2_kernel<<<14 * 42, 256, 0, stream>>>(ws + off_P1s, s_cw2, s_cb2, ws + off_P2s);

    // repack all three Wh matrices (P1s region now free) — one fused launch
    prep_wh_kernel<<<1536, 256, 0, stream>>>(s_Wh, w_Wh, d_Wh, wrS, wrW, wrD);

    // waveform branch convs
    wave_conv1_kernel<<<127, 256, 0, stream>>>(wave, w_cw1, w_cb1, ws + off_P1w);
    wave_conv2_kernel<<<62, 256, 0, stream>>>(ws + off_P1w, w_cw2, w_cb2, ws + off_P2w);

    // input projections
    xprojS_partial_kernel<<<256, 256, 0, stream>>>(ws + off_P2s, s_Wi, ws + off_partS);
    xprojS_reduce_kernel<<<56, 256, 0, stream>>>(ws + off_partS, s_b, ws + off_xprojS);
    xprojW_kernel<<<248, 256, 0, stream>>>(ws + off_P2w, w_Wi, w_b, ws + off_xprojW);

    // both encoder LSTMs concurrently (2 blocks on 2 CUs)
    lstm_enc5_kernel<<<2, 512, 0, stream>>>(wrS, ws + off_xprojS, ws + off_sh, ws + off_sc,
                                            wrW, ws + off_xprojW, ws + off_wh, ws + off_wc);

    // reducers + decoder precompute (also resets decoder sync counter)
    reduce_state_kernel<<<1, 256, 0, stream>>>(ws + off_sh, ws + off_sc, ws + off_wh, ws + off_wc,
                                               rh_w, rh_b, rc_w, rc_b, ws + off_h0, ws + off_c0);
    a01_kernel<<<8, 256, 0, stream>>>(emb, d_Wi, d_b, ws + off_a01, syncc);

    // sequential decoder chain (critical path) — 2 CUs, register-resident weight halves
    lstm_dec10_kernel<<<2, 512, 0, stream>>>(wrD, ws + off_a01, tok, ws + off_h0, ws + off_c0,
                                             h_uniq, rid, lrec, gpar, xg, syncc);

    // parallel epilogue: project unique rows only, then scatter to output
    proj_softmax_kernel<<<NSTEP / 4, 256, 0, stream>>>(h_uniq, out_w, out_b, gpar, ptab);
    scatter_out_kernel<<<19200, 256, 0, stream>>>(ptab, rid, lrec, gpar, tok, out);
}

// Round 6
// 1354.259 us; speedup vs baseline: 1.3960x; 1.3960x over previous
//
#include <hip/hip_runtime.h>
#include <hip/hip_bf16.h>
#include <stdint.h>

// ---------------- model dims ----------------
#define V_   128
#define L_   300
#define EU_  256
#define GU_  1024    // 4*EU
#define NSTEP (299*128)   // 38272 decoder steps

// Encoder weight layout (lane-pair k-split) for wrS/wrW:
//   u = j>>1, kh = j&1; p<52 reg / p>=52 LDS at WL4_OFF.
#define WL4_OFF  26624   // uint4 offset of LDS-resident weight part (encoder layout)

// Decoder weight layout (R2/dec6 layout — empirically best: 591us):
//   512 threads, thread j owns 2 gate columns: u=j&255, hi=j>>8,
//   colA = u + hi*512 (gates i/g), colB = colA + 256 (gates f/o).
//   wr4 [26][1024][4] dwords : kp=4q+p, kp<104 -> VGPR/AGPR-resident
//   wa/wb [6][512] uint4     : kp 104+ -> LDS
#define WLA_OFF  106496
#define WLB_OFF  118784
#define TOL      1e-4f
#define MEMO_T   32      // max memoized trajectory length (abort build past this)
#define LREC_NONE 0xFFFFFFFFu

typedef _Float16 h2 __attribute__((ext_vector_type(2)));

__device__ __forceinline__ float sigmoidf_(float x) { return 1.f / (1.f + __expf(-x)); }
__device__ __forceinline__ float tanhf_(float x) { return 2.f / (1.f + __expf(-2.f * x)) - 1.f; }

#if __has_builtin(__builtin_amdgcn_fdot2)
__device__ __forceinline__ float fdot2_(h2 a, h2 b, float c) { return __builtin_amdgcn_fdot2(a, b, c, false); }
#else
__device__ __forceinline__ float fdot2_(h2 a, h2 b, float c) {
    return c + (float)a.x * (float)b.x + (float)a.y * (float)b.y;
}
#endif

__device__ __forceinline__ h2 bch2(uint32_t u) {
    union { uint32_t u; h2 h; } x; x.u = u; return x.h;
}

__device__ __forceinline__ unsigned short bf16bits_(float f) {
    union { __hip_bfloat16 b; unsigned short s; } x;
    x.b = __float2bfloat16(f);
    return x.s;
}

// ---------------- encoder macros (lane-pair layout) ----------------
#define P13(M) M(0) M(1) M(2) M(3) M(4) M(5) M(6) M(7) M(8) M(9) M(10) M(11) M(12)

#define DECLW4(t) uint4 Wa##t, Wb##t, Wc##t, Wd##t;
#define LOADW4(t) Wa##t = w4[(4*(t)+0)*512 + j]; Wb##t = w4[(4*(t)+1)*512 + j]; \
                  Wc##t = w4[(4*(t)+2)*512 + j]; Wd##t = w4[(4*(t)+3)*512 + j];

#define DOTT(t) { uint4 hv = hp4[hb + (t)]; \
    a0 = fdot2_(bch2(Wa##t.x), bch2(hv.x), a0); a1 = fdot2_(bch2(Wa##t.y), bch2(hv.x), a1); \
    a2 = fdot2_(bch2(Wa##t.z), bch2(hv.x), a2); a3 = fdot2_(bch2(Wa##t.w), bch2(hv.x), a3); \
    b0 = fdot2_(bch2(Wb##t.x), bch2(hv.y), b0); b1 = fdot2_(bch2(Wb##t.y), bch2(hv.y), b1); \
    b2 = fdot2_(bch2(Wb##t.z), bch2(hv.y), b2); b3 = fdot2_(bch2(Wb##t.w), bch2(hv.y), b3); \
    a0 = fdot2_(bch2(Wc##t.x), bch2(hv.z), a0); a1 = fdot2_(bch2(Wc##t.y), bch2(hv.z), a1); \
    a2 = fdot2_(bch2(Wc##t.z), bch2(hv.z), a2); a3 = fdot2_(bch2(Wc##t.w), bch2(hv.z), a3); \
    b0 = fdot2_(bch2(Wd##t.x), bch2(hv.w), b0); b1 = fdot2_(bch2(Wd##t.y), bch2(hv.w), b1); \
    b2 = fdot2_(bch2(Wd##t.z), bch2(hv.w), b2); b3 = fdot2_(bch2(Wd##t.w), bch2(hv.w), b3); }

#define DOTL(tt) { uint4 hv = hp4[hb + 13 + (tt)]; \
    uint4 w0 = wl_s[((tt)*4+0)*512 + j]; uint4 w1 = wl_s[((tt)*4+1)*512 + j]; \
    uint4 w2 = wl_s[((tt)*4+2)*512 + j]; uint4 w3 = wl_s[((tt)*4+3)*512 + j]; \
    a0 = fdot2_(bch2(w0.x), bch2(hv.x), a0); a1 = fdot2_(bch2(w0.y), bch2(hv.x), a1); \
    a2 = fdot2_(bch2(w0.z), bch2(hv.x), a2); a3 = fdot2_(bch2(w0.w), bch2(hv.x), a3); \
    b0 = fdot2_(bch2(w1.x), bch2(hv.y), b0); b1 = fdot2_(bch2(w1.y), bch2(hv.y), b1); \
    b2 = fdot2_(bch2(w1.z), bch2(hv.y), b2); b3 = fdot2_(bch2(w1.w), bch2(hv.y), b3); \
    a0 = fdot2_(bch2(w2.x), bch2(hv.z), a0); a1 = fdot2_(bch2(w2.y), bch2(hv.z), a1); \
    a2 = fdot2_(bch2(w2.z), bch2(hv.z), a2); a3 = fdot2_(bch2(w2.w), bch2(hv.z), a3); \
    b0 = fdot2_(bch2(w3.x), bch2(hv.w), b0); b1 = fdot2_(bch2(w3.y), bch2(hv.w), b1); \
    b2 = fdot2_(bch2(w3.z), bch2(hv.w), b2); b3 = fdot2_(bch2(w3.w), bch2(hv.w), b3); }

#define DOTS_ALL4() \
    float a0 = 0.f, a1 = 0.f, a2 = 0.f, a3 = 0.f; \
    float b0 = 0.f, b1 = 0.f, b2 = 0.f, b3 = 0.f; \
    { const uint4* hp4 = (const uint4*)hp; const int hb = kh * 16; \
      P13(DOTT) \
      DOTL(0) DOTL(1) DOTL(2) }

// ---------------- decoder macros (R2/dec6 layout, 4-chain accumulators) ----------------
#define Q26(M) M(0) M(1) M(2) M(3) M(4) M(5) M(6) M(7) M(8) M(9) M(10) M(11) M(12) \
               M(13) M(14) M(15) M(16) M(17) M(18) M(19) M(20) M(21) M(22) M(23) M(24) M(25)

#define DECLW(q) uint4 wA##q, wB##q;
#define LOADW(q) wA##q = w4[(q) * 1024 + colA]; wB##q = w4[(q) * 1024 + colB];
#define DOTQ(q) { uint4 hv = hp4[q]; \
    aA0 = fdot2_(bch2(wA##q.x), bch2(hv.x), aA0); aB0 = fdot2_(bch2(wB##q.x), bch2(hv.x), aB0); \
    aA1 = fdot2_(bch2(wA##q.y), bch2(hv.y), aA1); aB1 = fdot2_(bch2(wB##q.y), bch2(hv.y), aB1); \
    aA2 = fdot2_(bch2(wA##q.z), bch2(hv.z), aA2); aB2 = fdot2_(bch2(wB##q.z), bch2(hv.z), aB2); \
    aA3 = fdot2_(bch2(wA##q.w), bch2(hv.w), aA3); aB3 = fdot2_(bch2(wB##q.w), bch2(hv.w), aB3); }

#define DOTS_ALL() \
    float aA, aB; \
    { float aA0 = 0.f, aA1 = 0.f, aA2 = 0.f, aA3 = 0.f; \
      float aB0 = 0.f, aB1 = 0.f, aB2 = 0.f, aB3 = 0.f; \
      const uint4* hp4 = (const uint4*)hp; \
      Q26(DOTQ) \
      _Pragma("unroll") \
      for (int qq = 0; qq < 6; ++qq) { \
          uint4 hv = hp4[26 + qq]; \
          uint4 wva = wa_s[qq * 512 + j]; \
          uint4 wvb = wb_s[qq * 512 + j]; \
          aA0 = fdot2_(bch2(wva.x), bch2(hv.x), aA0); aB0 = fdot2_(bch2(wva.y), bch2(hv.x), aB0); \
          aA1 = fdot2_(bch2(wva.z), bch2(hv.y), aA1); aB1 = fdot2_(bch2(wva.w), bch2(hv.y), aB1); \
          aA2 = fdot2_(bch2(wvb.x), bch2(hv.z), aA2); aB2 = fdot2_(bch2(wvb.y), bch2(hv.z), aB2); \
          aA3 = fdot2_(bch2(wvb.z), bch2(hv.w), aA3); aB3 = fdot2_(bch2(wvb.w), bch2(hv.w), aB3); } \
      aA = (aA0 + aA1) + (aA2 + aA3); aB = (aB0 + aB1) + (aB2 + aB3); }

// ---------------- weight repack: encoder lane-pair (m<2), decoder dec6 layout (m==2) ------
__global__ void prep_wh_kernel(const float* __restrict__ WhS, const float* __restrict__ WhW,
                               const float* __restrict__ WhD, uint32_t* __restrict__ wS,
                               uint32_t* __restrict__ wW, uint32_t* __restrict__ wD) {
    int bi = blockIdx.x;           // 1536 blocks = 3 matrices x 512
    int m = bi >> 9;
    const float* Wh = (m == 0) ? WhS : (m == 1) ? WhW : WhD;
    uint32_t* wbuf = (m == 0) ? wS : (m == 1) ? wW : wD;
    int idx = (bi & 511) * 256 + threadIdx.x;   // 131072 dwords
    int kp = idx >> 10, col = idx & 1023;
    union { _Float16 f[2]; uint32_t u; } p;
    p.f[0] = (_Float16)Wh[(2 * kp) * 1024 + col];
    p.f[1] = (_Float16)Wh[(2 * kp + 1) * 1024 + col];
    int g = col >> 8, u = col & 255;
    if (m < 2) {
        int kh = kp >> 6, pp = kp & 63;
        int j = (u << 1) | kh;                       // lane-pair mapping
        int dst = (pp < 52) ? ((pp * 512 + j) * 4 + g)
                            : (WL4_OFF * 4 + ((pp - 52) * 512 + j) * 4 + g);
        wbuf[dst] = p.u;
    } else {
        if (kp < 104) {
            wbuf[(kp >> 2) * 4096 + col * 4 + (kp & 3)] = p.u;
        } else {
            int kk = kp - 104, qq = kk >> 2, r = kk & 3;
            int half = r >> 1, pi = r & 1;
            int jj = u + (g >> 1) * 256, ab = g & 1;
            int base = half ? WLB_OFF : WLA_OFF;
            wbuf[base + (qq * 512 + jj) * 4 + pi * 2 + ab] = p.u;
        }
    }
}

// ---------------- fused encoder LSTMs: block 0 = stft (T=14), block 1 = wave (T=62) -------
__global__ __launch_bounds__(512, 2) __attribute__((amdgpu_waves_per_eu(2, 2)))
void lstm_enc5_kernel(const uint32_t* __restrict__ wS, const float* __restrict__ xpS,
                      float* __restrict__ shp, float* __restrict__ scp,
                      const uint32_t* __restrict__ wW, const float* __restrict__ xpW,
                      float* __restrict__ whp, float* __restrict__ wcp) {
    __shared__ uint4 wl_s[12 * 512];               // 96 KiB
    __shared__ __align__(16) uint32_t h_pk[2][128];
    const uint32_t* wbuf = blockIdx.x ? wW : wS;
    const float* xp = blockIdx.x ? xpW : xpS;
    float* h_out = blockIdx.x ? whp : shp;
    float* c_out = blockIdx.x ? wcp : scp;
    int T = blockIdx.x ? 62 : 14;
    int j = threadIdx.x;
    int u = j >> 1, kh = j & 1;
    const uint4* w4 = (const uint4*)wbuf;
    P13(DECLW4)
    P13(LOADW4)
    for (int i = j; i < 6144; i += 512) wl_s[i] = w4[WL4_OFF + i];
    if (j < 128) h_pk[0][j] = 0;
    float c = 0.f, h = 0.f;
    __syncthreads();
    int cur = 0;
    for (int t = 0; t < T; ++t) {
        const uint32_t* hp = &h_pk[cur][0];
        DOTS_ALL4()
        float s0 = a0 + b0, s1 = a1 + b1, s2 = a2 + b2, s3 = a3 + b3;
        const float* xr = xp + t * 1024;
        float zi = s0 + __shfl_xor(s0, 1) + xr[u];
        float zf = s1 + __shfl_xor(s1, 1) + xr[256 + u];
        float zg = s2 + __shfl_xor(s2, 1) + xr[512 + u];
        float zo = s3 + __shfl_xor(s3, 1) + xr[768 + u];
        c = sigmoidf_(zf) * c + sigmoidf_(zi) * tanhf_(zg);
        h = sigmoidf_(zo) * tanhf_(c);
        if (!kh) ((_Float16*)&h_pk[cur ^ 1][0])[u] = (_Float16)h;
        __syncthreads();
        cur ^= 1;
    }
    if (!kh) { h_out[u] = h; c_out[u] = c; }
}

// ---------------- decoder chain: dec6 structure + keyed RECOVERY memoization ----------------
// Best-known single-CU step structure (R2, 591us) + new level of dedup: the re-convergence
// trajectory after a TRUNCATED memo replay is fully determined by the truncation length M
// (start state = memo_st[M-1], all-a0 steps). First occurrence of each M records
// {base id, len, end state}; repeats replay in O(1): batch rid write + f16 state restore.
// fpid = id of the last row whose value matches the current state (replaces implicit uc-1).
__global__ __launch_bounds__(512, 2) __attribute__((amdgpu_waves_per_eu(2, 2)))
void lstm_dec11_kernel(const uint32_t* __restrict__ wbuf, const float* __restrict__ a01,
                       const int* __restrict__ tok, const float* __restrict__ h0,
                       const float* __restrict__ c0, __hip_bfloat16* __restrict__ uniq,
                       uint32_t* __restrict__ rid, uint32_t* __restrict__ lrec,
                       int* __restrict__ gpar, uint32_t* __restrict__ recg) {
    __shared__ uint4 wa_s[6 * 512];
    __shared__ uint4 wb_s[6 * 512];
    __shared__ __align__(16) uint32_t h_pk[2][128];
    __shared__ float zgo[256][2];
    __shared__ int flagv[2][4];
    __shared__ uint32_t memo_st[MEMO_T * 256];     // f16 h | f16 c per (memo step, u)
    __shared__ int tok_s[304];
    __shared__ int rec_valid_s[MEMO_T];            // uniform all-thread writes (no race)
    __shared__ int rec_len_s[MEMO_T];
    __shared__ int rec_base_s[MEMO_T];
    int j = threadIdx.x;
    int u = j & 255, hi = j >> 8;
    int colA = u + hi * 512, colB = colA + 256;
    const uint4* w4 = (const uint4*)wbuf;
    Q26(DECLW)
    Q26(LOADW)
    const uint4* srcA = (const uint4*)(wbuf + WLA_OFF);
    const uint4* srcB = (const uint4*)(wbuf + WLB_OFF);
    for (int i = j; i < 3072; i += 512) { wa_s[i] = srcA[i]; wb_s[i] = srcB[i]; }
    for (int i = j; i < 299; i += 512) tok_s[i] = tok[i];
    if (j < MEMO_T) rec_valid_s[j] = 0;
    float a0A = a01[colA], a0B = a01[colB];
    float a1A = a01[1024 + colA], a1B = a01[1024 + colB];
    float h = 0.f, c = 0.f;
    if (!hi) {
        h = h0[u];
        c = c0[u];
        ((_Float16*)&h_pk[0][0])[u] = (_Float16)h;
    }
    __syncthreads();
    int cur = 0;
    bool prev_a0 = false, stat = false;
    bool memo_valid = false, building = false;
    bool rbuild = false;
    int rkey = 0, rb0 = 0;
    int bidx = 0, memo_len = 0, mid0 = 0;
    int uc = 0, fpid = 0, step = 0, prk = -1;
#pragma unroll 1
    for (int l = 0; l < 299; ++l) {
        int tk = tok_s[l];
        // canonical l: full replay guaranteed, ends at the fixed point -> skip entirely
        if (stat && memo_valid && tk <= 128 - memo_len) {
            if (j == 0) lrec[l] = (uint32_t)fpid;
            step += 128;
            prev_a0 = true;
            prk = -1;
            continue;
        }
        if (j == 0) lrec[l] = LREC_NONE;
        int v = 0;
        // pending recovery (previous l ended with a truncated replay of length upk)
        int upk = prk;
        prk = -1;
        if (upk > 0 && upk < MEMO_T) {
            if (rec_valid_s[upk] && tk >= rec_len_s[upk]) {
                // replay recorded recovery: contiguous ids + f16 end-state restore
                int n = rec_len_s[upk], rb = rec_base_s[upk];
                if (j < n) rid[step + j] = (uint32_t)(rb + j);
                union { uint32_t w; _Float16 f[2]; } s;
                s.w = recg[upk * 256 + u];
                h = (float)s.f[0];
                c = (float)s.f[1];
                if (!hi) ((_Float16*)&h_pk[cur][0])[u] = s.f[0];
                fpid = rb + n - 1;
                stat = true;
                prev_a0 = true;
                step += n;
                v = n;
                __syncthreads();
            } else if (!rec_valid_s[upk] && !rbuild) {
                rbuild = true;      // record this recovery (aborts on isa1)
                rkey = upk;
                rb0 = uc;
            }
        }
        while (v < 128) {
            if (stat && v != tk) {
                // stationary under a0: rows == fixed-point row fpid; write ids only
                int nxt = (v < tk) ? tk : 128;
                int cnt = nxt - v;
                if (j < cnt) rid[step + j] = (uint32_t)fpid;
                step += cnt;
                v = nxt;
                continue;
            }
            if (v == tk && stat && memo_valid) {
                // replay memoized perturbation trajectory: ids only + state restore
                int M = (memo_len < 128 - v) ? memo_len : (128 - v);
                if (j < M) rid[step + j] = (uint32_t)(mid0 + j);
                if (!hi) {
                    union { uint32_t w; _Float16 f[2]; } s;
                    s.w = memo_st[(M - 1) * 256 + u];
                    h = (float)s.f[0];
                    c = (float)s.f[1];
                    ((_Float16*)&h_pk[cur][0])[u] = s.f[0];
                }
                step += M;
                v += M;
                if (M == memo_len) { stat = true; prev_a0 = true; }
                else { stat = false; prev_a0 = (M > 1); prk = M; }  // truncation -> recovery next l
                __syncthreads();
                continue;
            }
            // normal computed step (records memo / recovery during builds)
            bool isa1 = (v == tk);
            if (isa1 && stat && !memo_valid && !building) { building = true; bidx = 0; mid0 = uc; }
            const uint32_t* hp = &h_pk[cur][0];
            DOTS_ALL()
            float zA = aA + (isa1 ? a1A : a0A);
            float zB = aB + (isa1 ? a1B : a0B);
            if (hi) { zgo[u][0] = zA; zgo[u][1] = zB; }
            __syncthreads();
            if (!hi) {
                float zg = zgo[u][0], zo = zgo[u][1];
                float cn = sigmoidf_(zB) * c + sigmoidf_(zA) * tanhf_(zg);
                float hn = sigmoidf_(zo) * tanhf_(cn);
                bool ok = (fabsf(hn - h) <= TOL) && (fabsf(cn - c) <= TOL) && !isa1 && prev_a0;
                unsigned long long bal = __ballot(ok ? 1 : 0);
                if ((j & 63) == 0) flagv[cur][j >> 6] = (bal == ~0ull) ? 1 : 0;
                h = hn;
                c = cn;
                unsigned short hb = bf16bits_(hn);
                ((unsigned short*)uniq)[(size_t)uc * 256 + u] = hb;
                if (u == 0) rid[step] = (uint32_t)uc;
                ((_Float16*)&h_pk[cur ^ 1][0])[u] = (_Float16)hn;
                if (building) {
                    union { uint32_t w; _Float16 f[2]; } s;
                    s.f[0] = (_Float16)hn;
                    s.f[1] = (_Float16)cn;
                    memo_st[bidx * 256 + u] = s.w;
                }
            }
            __syncthreads();
            stat = flagv[cur][0] && flagv[cur][1] && flagv[cur][2] && flagv[cur][3];
            cur ^= 1;
            prev_a0 = !isa1;
            fpid = uc;
            ++step;
            ++v;
            ++uc;
            if (building) {
                if (stat) { memo_len = bidx + 1; memo_valid = true; building = false; }
                else if (bidx + 1 >= MEMO_T) building = false;  // abort: too long
                else ++bidx;
            }
            if (rbuild) {
                if (isa1) {
                    rbuild = false;                 // a1 step breaks key-M determinism
                } else if (stat) {
                    int rl = uc - rb0;              // ids rb0..uc-1 are this recovery
                    rec_len_s[rkey] = rl;           // uniform same-value writes by all threads
                    rec_base_s[rkey] = rb0;
                    if (rl <= 120) {
                        if (!hi) {
                            union { uint32_t w; _Float16 f[2]; } s;
                            s.f[0] = (_Float16)h;
                            s.f[1] = (_Float16)c;
                            recg[rkey * 256 + u] = s.w;
                        }
                        rec_valid_s[rkey] = 1;
                    }
                    rbuild = false;
                }
            }
        }
        building = false;  // abort any memo build crossing an l boundary (rbuild may span)
    }
    if (j == 0) {
        gpar[0] = uc;                               // unique-row count
        gpar[1] = mid0;                             // memo base row id
        gpar[2] = memo_valid ? memo_len : 0;        // memo length (0 = no memo)
    }
}

// ---------------- tok extraction ----------------
__global__ void tok_kernel(const float* __restrict__ din, int* __restrict__ tok) {
    int l = blockIdx.x * 64 + threadIdx.x;
    if (l >= 299) return;
    int t = 0;
    for (int v = 0; v < 128; ++v)
        if (din[l * 128 + v] > 0.5f) t = v;
    tok[l] = t;
}

// ---------------- STFT conv1 (3x3x1->256) + relu + 2x2 maxpool ----------------
__global__ void stft_conv1_kernel(const float* __restrict__ in, const float* __restrict__ w,
                                  const float* __restrict__ b, float* __restrict__ out) {
    int c = threadIdx.x;
    int blk = blockIdx.x;
    int pw = blk % 255, ph = blk / 255;
    int h0 = 2 * ph, w0 = 2 * pw;
    float pin[4][4];
#pragma unroll
    for (int r = 0; r < 4; ++r)
#pragma unroll
        for (int s = 0; s < 4; ++s) pin[r][s] = in[(h0 + r) * 513 + (w0 + s)];
    float acc[2][2] = {};
#pragma unroll
    for (int dh = 0; dh < 3; ++dh)
#pragma unroll
        for (int dw = 0; dw < 3; ++dw) {
            float wv = w[(dh * 3 + dw) * 256 + c];
            acc[0][0] += pin[dh][dw] * wv;
            acc[0][1] += pin[dh][dw + 1] * wv;
            acc[1][0] += pin[dh + 1][dw] * wv;
            acc[1][1] += pin[dh + 1][dw + 1] * wv;
        }
    float m = fmaxf(fmaxf(acc[0][0], acc[0][1]), fmaxf(acc[1][0], acc[1][1]));
    out[(ph * 255 + pw) * 256 + c] = fmaxf(m + b[c], 0.f);
}

// ---------------- STFT conv2 (3x3x256->256) + relu + 2x2 maxpool, float4 LDS reads -------
__global__ void stft_conv2_kernel(const float* __restrict__ P1, const float* __restrict__ w,
                                  const float* __restrict__ b, float* __restrict__ out) {
    __shared__ __align__(16) float patch[4 * 8 * 256];
    int c = threadIdx.x;
    int blk = blockIdx.x;
    int pwg = blk % 42, ph = blk / 42;
    int pw0 = pwg * 3;
    int r0 = 2 * ph, c0 = 2 * pw0;
    for (int i = c; i < 4 * 8 * 256; i += 256) {
        int ci = i & 255;
        int t = i >> 8;
        int cc = t & 7, r = t >> 3;
        patch[i] = P1[((r0 + r) * 255 + (c0 + cc)) * 256 + ci];
    }
    __syncthreads();
    const float4* patch4 = (const float4*)patch;
    float acc[3][2][2] = {};
    for (int dh = 0; dh < 3; ++dh) {
        for (int ci = 0; ci < 256; ci += 4) {
            float4 p0[8], p1[8];
#pragma unroll
            for (int x = 0; x < 8; ++x) {
                p0[x] = patch4[((dh * 8 + x) * 256 + ci) >> 2];
                p1[x] = patch4[(((dh + 1) * 8 + x) * 256 + ci) >> 2];
            }
#pragma unroll
            for (int r = 0; r < 4; ++r) {
#pragma unroll
                for (int dw = 0; dw < 3; ++dw) {
                    float wv = w[((dh * 3 + dw) * 256 + ci + r) * 256 + c];
#pragma unroll
                    for (int o = 0; o < 3; ++o)
#pragma unroll
                        for (int s = 0; s < 2; ++s) {
                            int x = 2 * o + s + dw;
                            acc[o][0][s] += ((const float*)&p0[x])[r] * wv;
                            acc[o][1][s] += ((const float*)&p1[x])[r] * wv;
                        }
                }
            }
        }
    }
    float bv = b[c];
#pragma unroll
    for (int o = 0; o < 3; ++o) {
        float m = fmaxf(fmaxf(acc[o][0][0], acc[o][0][1]), fmaxf(acc[o][1][0], acc[o][1][1]));
        out[(ph * 126 + (pw0 + o)) * 256 + c] = fmaxf(m + bv, 0.f);
    }
}

// ---------------- STFT input projection: X[14,32256] @ Wi[32256,1024], split-K ------------
__global__ void xprojS_partial_kernel(const float* __restrict__ X, const float* __restrict__ Wi,
                                      float* __restrict__ part) {
    __shared__ __align__(16) float xbuf[14 * 504];
    int tid = threadIdx.x;
    int kc = blockIdx.x & 63;
    int cb = blockIdx.x >> 6;
    int col = cb * 256 + tid;
    int k0 = kc * 504;
    for (int i = tid; i < 14 * 504; i += 256) {
        int t = i / 504;
        int kk = i - t * 504;
        xbuf[i] = X[t * 32256 + k0 + kk];
    }
    __syncthreads();
    const float4* xb4 = (const float4*)xbuf;
    float acc[14] = {};
    for (int kk = 0; kk < 504; kk += 4) {
        float wv0 = Wi[(size_t)(k0 + kk) * 1024 + col];
        float wv1 = Wi[(size_t)(k0 + kk + 1) * 1024 + col];
        float wv2 = Wi[(size_t)(k0 + kk + 2) * 1024 + col];
        float wv3 = Wi[(size_t)(k0 + kk + 3) * 1024 + col];
#pragma unroll
        for (int t = 0; t < 14; ++t) {
            float4 xv = xb4[(t * 504 + kk) >> 2];
            acc[t] += xv.x * wv0 + xv.y * wv1 + xv.z * wv2 + xv.w * wv3;
        }
    }
#pragma unroll
    for (int t = 0; t < 14; ++t) part[(kc * 14 + t) * 1024 + col] = acc[t];
}

__global__ void xprojS_reduce_kernel(const float* __restrict__ part, const float* __restrict__ bias,
                                     float* __restrict__ xp) {
    int idx = blockIdx.x * 256 + threadIdx.x;  // < 14*1024
    int t = idx >> 10, col = idx & 1023;
    float s = bias[col];
    for (int kc = 0; kc < 64; ++kc) s += part[(kc * 14 + t) * 1024 + col];
    xp[idx] = s;
}

// ---------------- wave conv1 (k=3, 1024->256) + relu + pool2, float4 LDS reads ------------
__global__ void wave_conv1_kernel(const float* __restrict__ in, const float* __restrict__ w,
                                  const float* __restrict__ b, float* __restrict__ out) {
    __shared__ __align__(16) float patch[4 * 1024];
    int c = threadIdx.x, t = blockIdx.x;
    for (int i = c; i < 4 * 1024; i += 256) patch[i] = in[(2 * t) * 1024 + i];
    __syncthreads();
    const float4* patch4 = (const float4*)patch;
    float acc0 = 0.f, acc1 = 0.f;
    for (int dt = 0; dt < 3; ++dt)
        for (int ci = 0; ci < 1024; ci += 4) {
            float4 q0 = patch4[(dt * 1024 + ci) >> 2];
            float4 q1 = patch4[((dt + 1) * 1024 + ci) >> 2];
#pragma unroll
            for (int r = 0; r < 4; ++r) {
                float wv = w[(dt * 1024 + ci + r) * 256 + c];
                acc0 += ((const float*)&q0)[r] * wv;
                acc1 += ((const float*)&q1)[r] * wv;
            }
        }
    out[t * 256 + c] = fmaxf(fmaxf(acc0, acc1) + b[c], 0.f);
}

// ---------------- wave conv2 (k=3, 256->256) + relu + pool2, float4 LDS reads -------------
__global__ void wave_conv2_kernel(const float* __restrict__ in, const float* __restrict__ w,
                                  const float* __restrict__ b, float* __restrict__ out) {
    __shared__ __align__(16) float patch[4 * 256];
    int c = threadIdx.x, t = blockIdx.x;
    for (int i = c; i < 4 * 256; i += 256) patch[i] = in[(2 * t) * 256 + i];
    __syncthreads();
    const float4* patch4 = (const float4*)patch;
    float acc0 = 0.f, acc1 = 0.f;
    for (int dt = 0; dt < 3; ++dt)
        for (int ci = 0; ci < 256; ci += 4) {
            float4 q0 = patch4[(dt * 256 + ci) >> 2];
            float4 q1 = patch4[((dt + 1) * 256 + ci) >> 2];
#pragma unroll
            for (int r = 0; r < 4; ++r) {
                float wv = w[(dt * 256 + ci + r) * 256 + c];
                acc0 += ((const float*)&q0)[r] * wv;
                acc1 += ((const float*)&q1)[r] * wv;
            }
        }
    out[t * 256 + c] = fmaxf(fmaxf(acc0, acc1) + b[c], 0.f);
}

// ---------------- wave input projection X[62,256] @ Wi[256,1024] + b ----------------
__global__ void xprojW_kernel(const float* __restrict__ X, const float* __restrict__ Wi,
                              const float* __restrict__ bias, float* __restrict__ xp) {
    int idx = blockIdx.x * 256 + threadIdx.x;  // 62*1024
    int t = idx >> 10, col = idx & 1023;
    float s = bias[col];
    for (int k = 0; k < 256; ++k) s += X[t * 256 + k] * Wi[k * 1024 + col];
    xp[idx] = s;
}

// ---------------- state reducers ----------------
__global__ void reduce_state_kernel(const float* __restrict__ sh, const float* __restrict__ sc,
                                    const float* __restrict__ wh, const float* __restrict__ wc,
                                    const float* __restrict__ rhw, const float* __restrict__ rhb,
                                    const float* __restrict__ rcw, const float* __restrict__ rcb,
                                    float* __restrict__ h0, float* __restrict__ c0) {
    int m = threadIdx.x;  // 256
    float ah = rhb[m], ac = rcb[m];
    for (int k = 0; k < 256; ++k) {
        ah += sh[k] * rhw[k * 256 + m];
        ac += sc[k] * rcw[k * 256 + m];
    }
    for (int k = 0; k < 256; ++k) {
        ah += wh[k] * rhw[(256 + k) * 256 + m];
        ac += wc[k] * rcw[(256 + k) * 256 + m];
    }
    h0[m] = ah;
    c0[m] = ac;
}

// ---------------- a0/a1 = emb[s] @ d_Wi + d_b ----------------
__global__ void a01_kernel(const float* __restrict__ emb, const float* __restrict__ Wi,
                           const float* __restrict__ bias, float* __restrict__ a01) {
    int idx = blockIdx.x * 256 + threadIdx.x;  // 2048
    int s = idx >> 10, j = idx & 1023;
    float acc = bias[j];
    for (int k = 0; k < 256; ++k) acc += emb[s * 256 + k] * Wi[k * 1024 + j];
    a01[idx] = acc;
}

// ---------------- projection + softmax over UNIQUE rows: 4 rows/block ----------------
__global__ __launch_bounds__(256) void proj_softmax_kernel(const __hip_bfloat16* __restrict__ uniq,
                                                           const float* __restrict__ Wo,
                                                           const float* __restrict__ bo,
                                                           const int* __restrict__ gpar,
                                                           float* __restrict__ ptab) {
    __shared__ float hrows[4][256];
    __shared__ float llds[4][128];
    int tid = threadIdx.x;
    int rbase = blockIdx.x * 4;
    int U = gpar[0];
    if (rbase >= U) return;   // early-exit: only ~uc/4 blocks do work
    for (int i = tid; i < 1024; i += 256)
        hrows[i >> 8][i & 255] = __bfloat162float(uniq[(size_t)rbase * 256 + i]);
    __syncthreads();
    int w = tid & 127, half = tid >> 7;
    int k0 = half * 128;
    float acc[4] = {};
    for (int k = 0; k < 128; ++k) {
        float wv = Wo[(k0 + k) * 128 + w];
#pragma unroll
        for (int r = 0; r < 4; ++r) acc[r] += hrows[r][k0 + k] * wv;
    }
    if (half == 0) {
#pragma unroll
        for (int r = 0; r < 4; ++r) llds[r][w] = acc[r] + bo[w];
    }
    __syncthreads();
    if (half == 1) {
#pragma unroll
        for (int r = 0; r < 4; ++r) llds[r][w] += acc[r];
    }
    __syncthreads();
    int rr = tid >> 6, lane = tid & 63;
    float x0 = llds[rr][lane], x1 = llds[rr][lane + 64];
    float mx = fmaxf(x0, x1);
    for (int off = 32; off > 0; off >>= 1) mx = fmaxf(mx, __shfl_xor(mx, off));
    float e0 = __expf(x0 - mx), e1 = __expf(x1 - mx);
    float sm = e0 + e1;
    for (int off = 32; off > 0; off >>= 1) sm += __shfl_xor(sm, off);
    float inv = 1.f / sm;
    int row = rbase + rr;
    float* op = ptab + (size_t)row * 128;
    op[lane] = e0 * inv;
    op[lane + 64] = e1 * inv;
}

// ---------------- scatter: out[v,l,:] = ptab[id(l,v)]  (l==299 -> 0) ----------------
__global__ void scatter_out_kernel(const float* __restrict__ ptab,
                                   const uint32_t* __restrict__ rid,
                                   const uint32_t* __restrict__ lrec,
                                   const int* __restrict__ gpar,
                                   const int* __restrict__ tok,
                                   float* __restrict__ out) {
    int idx = blockIdx.x * 256 + threadIdx.x;  // 300*128*128 = 4915200
    int w = idx & 127;
    int step = idx >> 7;       // l*128 + v, l in [0,300)
    int l = step >> 7;
    int v = step & 127;
    float val = 0.f;
    if (l < 299) {
        uint32_t fr = lrec[l];
        uint32_t id;
        if (fr == LREC_NONE) {
            id = rid[step];
        } else {
            int tk = tok[l];
            int d = v - tk;
            int mlen = gpar[2];
            id = (d >= 0 && d < mlen) ? (uint32_t)(gpar[1] + d) : fr;
        }
        val = ptab[(size_t)id * 128 + w];
    }
    out[((size_t)v * 300 + l) * 128 + w] = val;
}

extern "C" void kernel_launch(void* const* d_in, const int* in_sizes, int n_in, void* d_out,
                              int out_size, void* d_ws, size_t ws_size, hipStream_t stream) {
    const float* stft = (const float*)d_in[0];
    const float* wave = (const float*)d_in[1];
    const float* din = (const float*)d_in[2];
    const float* s_cw1 = (const float*)d_in[3];
    const float* s_cb1 = (const float*)d_in[4];
    const float* s_cw2 = (const float*)d_in[5];
    const float* s_cb2 = (const float*)d_in[6];
    const float* s_Wi = (const float*)d_in[7];
    const float* s_Wh = (const float*)d_in[8];
    const float* s_b = (const float*)d_in[9];
    const float* w_cw1 = (const float*)d_in[10];
    const float* w_cb1 = (const float*)d_in[11];
    const float* w_cw2 = (const float*)d_in[12];
    const float* w_cb2 = (const float*)d_in[13];
    const float* w_Wi = (const float*)d_in[14];
    const float* w_Wh = (const float*)d_in[15];
    const float* w_b = (const float*)d_in[16];
    const float* rh_w = (const float*)d_in[17];
    const float* rh_b = (const float*)d_in[18];
    const float* rc_w = (const float*)d_in[19];
    const float* rc_b = (const float*)d_in[20];
    const float* emb = (const float*)d_in[21];
    const float* d_Wi = (const float*)d_in[22];
    const float* d_Wh = (const float*)d_in[23];
    const float* d_b = (const float*)d_in[24];
    const float* out_w = (const float*)d_in[25];
    const float* out_b = (const float*)d_in[26];
    float* out = (float*)d_out;
    float* ws = (float*)d_ws;

    // workspace layout (float offsets)
    const size_t off_P1s = 0;                         // 31*255*256 = 2023680 (reused for packed weights)
    const size_t off_P2s = off_P1s + 2023680;         // 14*126*256 = 451584
    const size_t off_partS = off_P2s + 451584;        // 64*14*1024 = 917504
    const size_t off_P1w = off_partS + 917504;        // 127*256 = 32512
    const size_t off_P2w = off_P1w + 32512;           // 62*256 = 15872
    const size_t off_xprojS = off_P2w + 15872;        // 14*1024
    const size_t off_xprojW = off_xprojS + 14336;     // 62*1024
    const size_t off_sh = off_xprojW + 63488;         // 4*256 states
    const size_t off_sc = off_sh + 256;
    const size_t off_wh = off_sc + 256;
    const size_t off_wc = off_wh + 256;
    const size_t off_h0 = off_wc + 256;
    const size_t off_c0 = off_h0 + 256;
    const size_t off_a01 = off_c0 + 256;              // 2048
    const size_t off_tok = off_a01 + 2048;            // 299 ints (512 slots)
    const size_t off_uniq = off_tok + 512;            // bf16 region: 38272*256 bf16 = 4898816 floats
    const size_t off_rid = off_uniq + 4898816;        // 38272 u32
    const size_t off_lrec = off_rid + 38272;          // 300 u32 (padded 320)
    const size_t off_gpar = off_lrec + 320;           // 3 ints (padded 64)
    const size_t off_recg = off_gpar + 64;            // 32*256 u32 recovery end states
    const size_t off_ptab = off_recg + 8192;          // 38272*128 floats (worst-case unique rows)
    __hip_bfloat16* h_uniq = (__hip_bfloat16*)(ws + off_uniq);
    uint32_t* rid = (uint32_t*)(ws + off_rid);
    uint32_t* lrec = (uint32_t*)(ws + off_lrec);
    int* gpar = (int*)(ws + off_gpar);
    uint32_t* recg = (uint32_t*)(ws + off_recg);
    float* ptab = ws + off_ptab;
    int* tok = (int*)(ws + off_tok);
    // packed f16 weights overlay the P1s region (free after stft_conv2): 3 x 131072 dwords
    uint32_t* wrS = (uint32_t*)(ws + off_P1s);
    uint32_t* wrW = wrS + 131072;
    uint32_t* wrD = wrW + 131072;

    tok_kernel<<<5, 64, 0, stream>>>(din, tok);

    // STFT conv pipeline (P1s in use until stft_conv2 completes)
    stft_conv1_kernel<<<31 * 255, 256, 0, stream>>>(stft, s_cw1, s_cb1, ws + off_P1s);
    stft_conv2_kernel<<<14 * 42, 256, 0, stream>>>(ws + off_P1s, s_cw2, s_cb2, ws + off_P2s);

    // repack all three Wh matrices (P1s region now free) — one fused launch
    prep_wh_kernel<<<1536, 256, 0, stream>>>(s_Wh, w_Wh, d_Wh, wrS, wrW, wrD);

    // waveform branch convs
    wave_conv1_kernel<<<127, 256, 0, stream>>>(wave, w_cw1, w_cb1, ws + off_P1w);
    wave_conv2_kernel<<<62, 256, 0, stream>>>(ws + off_P1w, w_cw2, w_cb2, ws + off_P2w);

    // input projections
    xprojS_partial_kernel<<<256, 256, 0, stream>>>(ws + off_P2s, s_Wi, ws + off_partS);
    xprojS_reduce_kernel<<<56, 256, 0, stream>>>(ws + off_partS, s_b, ws + off_xprojS);
    xprojW_kernel<<<248, 256, 0, stream>>>(ws + off_P2w, w_Wi, w_b, ws + off_xprojW);

    // both encoder LSTMs concurrently (2 blocks on 2 CUs)
    lstm_enc5_kernel<<<2, 512, 0, stream>>>(wrS, ws + off_xprojS, ws + off_sh, ws + off_sc,
                                            wrW, ws + off_xprojW, ws + off_wh, ws + off_wc);

    // reducers + decoder precompute
    reduce_state_kernel<<<1, 256, 0, stream>>>(ws + off_sh, ws + off_sc, ws + off_wh, ws + off_wc,
                                               rh_w, rh_b, rc_w, rc_b, ws + off_h0, ws + off_c0);
    a01_kernel<<<8, 256, 0, stream>>>(emb, d_Wi, d_b, ws + off_a01);

    // sequential decoder chain (critical path) — dec6 structure + recovery memoization
    lstm_dec11_kernel<<<1, 512, 0, stream>>>(wrD, ws + off_a01, tok, ws + off_h0, ws + off_c0,
                                             h_uniq, rid, lrec, gpar, recg);

    // parallel epilogue: project unique rows only, then scatter to output
    proj_softmax_kernel<<<NSTEP / 4, 256, 0, stream>>>(h_uniq, out_w, out_b, gpar, ptab);
    scatter_out_kernel<<<19200, 256, 0, stream>>>(ptab, rid, lrec, gpar, tok, out);
}

// Round 7
// 1152.783 us; speedup vs baseline: 1.6400x; 1.1748x over previous
//
#include <hip/hip_runtime.h>
#include <hip/hip_bf16.h>
#include <stdint.h>

// ---------------- model dims ----------------
#define V_   128
#define L_   300
#define EU_  256
#define GU_  1024    // 4*EU
#define NSTEP (299*128)   // 38272 decoder steps

// Encoder weight layout (lane-pair k-split) for wrS/wrW:
//   u = j>>1, kh = j&1; p<52 reg / p>=52 LDS at WL4_OFF.
#define WL4_OFF  26624   // uint4 offset of LDS-resident weight part (encoder layout)

// Decoder weight layout (R2/dec6 layout — empirically best step cost):
//   512 threads, thread j owns 2 gate columns: u=j&255, hi=j>>8,
//   colA = u + hi*512 (gates i/g), colB = colA + 256 (gates f/o).
//   wr4 [26][1024][4] dwords : kp=4q+p, kp<104 -> VGPR/AGPR-resident
//   wa/wb [6][512] uint4     : kp 104+ -> LDS
#define WLA_OFF  106496
#define WLB_OFF  118784
#define TOL      1e-4f
#define MEMO_T   32      // max memoized trajectory length (abort build past this)
#define LREC_NONE 0xFFFFFFFFu

typedef _Float16 h2 __attribute__((ext_vector_type(2)));

__device__ __forceinline__ float sigmoidf_(float x) { return 1.f / (1.f + __expf(-x)); }
__device__ __forceinline__ float tanhf_(float x) { return 2.f / (1.f + __expf(-2.f * x)) - 1.f; }

#if __has_builtin(__builtin_amdgcn_fdot2)
__device__ __forceinline__ float fdot2_(h2 a, h2 b, float c) { return __builtin_amdgcn_fdot2(a, b, c, false); }
#else
__device__ __forceinline__ float fdot2_(h2 a, h2 b, float c) {
    return c + (float)a.x * (float)b.x + (float)a.y * (float)b.y;
}
#endif

__device__ __forceinline__ h2 bch2(uint32_t u) {
    union { uint32_t u; h2 h; } x; x.u = u; return x.h;
}

__device__ __forceinline__ unsigned short bf16bits_(float f) {
    union { __hip_bfloat16 b; unsigned short s; } x;
    x.b = __float2bfloat16(f);
    return x.s;
}

// ---------------- encoder macros (lane-pair layout) ----------------
#define P13(M) M(0) M(1) M(2) M(3) M(4) M(5) M(6) M(7) M(8) M(9) M(10) M(11) M(12)

#define DECLW4(t) uint4 Wa##t, Wb##t, Wc##t, Wd##t;
#define LOADW4(t) Wa##t = w4[(4*(t)+0)*512 + j]; Wb##t = w4[(4*(t)+1)*512 + j]; \
                  Wc##t = w4[(4*(t)+2)*512 + j]; Wd##t = w4[(4*(t)+3)*512 + j];

#define DOTT(t) { uint4 hv = hp4[hb + (t)]; \
    a0 = fdot2_(bch2(Wa##t.x), bch2(hv.x), a0); a1 = fdot2_(bch2(Wa##t.y), bch2(hv.x), a1); \
    a2 = fdot2_(bch2(Wa##t.z), bch2(hv.x), a2); a3 = fdot2_(bch2(Wa##t.w), bch2(hv.x), a3); \
    b0 = fdot2_(bch2(Wb##t.x), bch2(hv.y), b0); b1 = fdot2_(bch2(Wb##t.y), bch2(hv.y), b1); \
    b2 = fdot2_(bch2(Wb##t.z), bch2(hv.y), b2); b3 = fdot2_(bch2(Wb##t.w), bch2(hv.y), b3); \
    a0 = fdot2_(bch2(Wc##t.x), bch2(hv.z), a0); a1 = fdot2_(bch2(Wc##t.y), bch2(hv.z), a1); \
    a2 = fdot2_(bch2(Wc##t.z), bch2(hv.z), a2); a3 = fdot2_(bch2(Wc##t.w), bch2(hv.z), a3); \
    b0 = fdot2_(bch2(Wd##t.x), bch2(hv.w), b0); b1 = fdot2_(bch2(Wd##t.y), bch2(hv.w), b1); \
    b2 = fdot2_(bch2(Wd##t.z), bch2(hv.w), b2); b3 = fdot2_(bch2(Wd##t.w), bch2(hv.w), b3); }

#define DOTL(tt) { uint4 hv = hp4[hb + 13 + (tt)]; \
    uint4 w0 = wl_s[((tt)*4+0)*512 + j]; uint4 w1 = wl_s[((tt)*4+1)*512 + j]; \
    uint4 w2 = wl_s[((tt)*4+2)*512 + j]; uint4 w3 = wl_s[((tt)*4+3)*512 + j]; \
    a0 = fdot2_(bch2(w0.x), bch2(hv.x), a0); a1 = fdot2_(bch2(w0.y), bch2(hv.x), a1); \
    a2 = fdot2_(bch2(w0.z), bch2(hv.x), a2); a3 = fdot2_(bch2(w0.w), bch2(hv.x), a3); \
    b0 = fdot2_(bch2(w1.x), bch2(hv.y), b0); b1 = fdot2_(bch2(w1.y), bch2(hv.y), b1); \
    b2 = fdot2_(bch2(w1.z), bch2(hv.y), b2); b3 = fdot2_(bch2(w1.w), bch2(hv.y), b3); \
    a0 = fdot2_(bch2(w2.x), bch2(hv.z), a0); a1 = fdot2_(bch2(w2.y), bch2(hv.z), a1); \
    a2 = fdot2_(bch2(w2.z), bch2(hv.z), a2); a3 = fdot2_(bch2(w2.w), bch2(hv.z), a3); \
    b0 = fdot2_(bch2(w3.x), bch2(hv.w), b0); b1 = fdot2_(bch2(w3.y), bch2(hv.w), b1); \
    b2 = fdot2_(bch2(w3.z), bch2(hv.w), b2); b3 = fdot2_(bch2(w3.w), bch2(hv.w), b3); }

#define DOTS_ALL4() \
    float a0 = 0.f, a1 = 0.f, a2 = 0.f, a3 = 0.f; \
    float b0 = 0.f, b1 = 0.f, b2 = 0.f, b3 = 0.f; \
    { const uint4* hp4 = (const uint4*)hp; const int hb = kh * 16; \
      P13(DOTT) \
      DOTL(0) DOTL(1) DOTL(2) }

// ---------------- decoder macros (R2/dec6 layout, 4-chain accumulators) ----------------
#define Q26(M) M(0) M(1) M(2) M(3) M(4) M(5) M(6) M(7) M(8) M(9) M(10) M(11) M(12) \
               M(13) M(14) M(15) M(16) M(17) M(18) M(19) M(20) M(21) M(22) M(23) M(24) M(25)

#define DECLW(q) uint4 wA##q, wB##q;
#define LOADW(q) wA##q = w4[(q) * 1024 + colA]; wB##q = w4[(q) * 1024 + colB];
#define DOTQ(q) { uint4 hv = hp4[q]; \
    aA0 = fdot2_(bch2(wA##q.x), bch2(hv.x), aA0); aB0 = fdot2_(bch2(wB##q.x), bch2(hv.x), aB0); \
    aA1 = fdot2_(bch2(wA##q.y), bch2(hv.y), aA1); aB1 = fdot2_(bch2(wB##q.y), bch2(hv.y), aB1); \
    aA2 = fdot2_(bch2(wA##q.z), bch2(hv.z), aA2); aB2 = fdot2_(bch2(wB##q.z), bch2(hv.z), aB2); \
    aA3 = fdot2_(bch2(wA##q.w), bch2(hv.w), aA3); aB3 = fdot2_(bch2(wB##q.w), bch2(hv.w), aB3); }

#define DOTS_ALL() \
    float aA, aB; \
    { float aA0 = 0.f, aA1 = 0.f, aA2 = 0.f, aA3 = 0.f; \
      float aB0 = 0.f, aB1 = 0.f, aB2 = 0.f, aB3 = 0.f; \
      const uint4* hp4 = (const uint4*)hp; \
      Q26(DOTQ) \
      _Pragma("unroll") \
      for (int qq = 0; qq < 6; ++qq) { \
          uint4 hv = hp4[26 + qq]; \
          uint4 wva = wa_s[qq * 512 + j]; \
          uint4 wvb = wb_s[qq * 512 + j]; \
          aA0 = fdot2_(bch2(wva.x), bch2(hv.x), aA0); aB0 = fdot2_(bch2(wva.y), bch2(hv.x), aB0); \
          aA1 = fdot2_(bch2(wva.z), bch2(hv.y), aA1); aB1 = fdot2_(bch2(wva.w), bch2(hv.y), aB1); \
          aA2 = fdot2_(bch2(wvb.x), bch2(hv.z), aA2); aB2 = fdot2_(bch2(wvb.y), bch2(hv.z), aB2); \
          aA3 = fdot2_(bch2(wvb.z), bch2(hv.w), aA3); aB3 = fdot2_(bch2(wvb.w), bch2(hv.w), aB3); } \
      aA = (aA0 + aA1) + (aA2 + aA3); aB = (aB0 + aB1) + (aB2 + aB3); }

// ---------------- weight repack: encoder lane-pair (m<2), decoder dec6 layout (m==2) ------
__global__ void prep_wh_kernel(const float* __restrict__ WhS, const float* __restrict__ WhW,
                               const float* __restrict__ WhD, uint32_t* __restrict__ wS,
                               uint32_t* __restrict__ wW, uint32_t* __restrict__ wD) {
    int bi = blockIdx.x;           // 1536 blocks = 3 matrices x 512
    int m = bi >> 9;
    const float* Wh = (m == 0) ? WhS : (m == 1) ? WhW : WhD;
    uint32_t* wbuf = (m == 0) ? wS : (m == 1) ? wW : wD;
    int idx = (bi & 511) * 256 + threadIdx.x;   // 131072 dwords
    int kp = idx >> 10, col = idx & 1023;
    union { _Float16 f[2]; uint32_t u; } p;
    p.f[0] = (_Float16)Wh[(2 * kp) * 1024 + col];
    p.f[1] = (_Float16)Wh[(2 * kp + 1) * 1024 + col];
    int g = col >> 8, u = col & 255;
    if (m < 2) {
        int kh = kp >> 6, pp = kp & 63;
        int j = (u << 1) | kh;                       // lane-pair mapping
        int dst = (pp < 52) ? ((pp * 512 + j) * 4 + g)
                            : (WL4_OFF * 4 + ((pp - 52) * 512 + j) * 4 + g);
        wbuf[dst] = p.u;
    } else {
        if (kp < 104) {
            wbuf[(kp >> 2) * 4096 + col * 4 + (kp & 3)] = p.u;
        } else {
            int kk = kp - 104, qq = kk >> 2, r = kk & 3;
            int half = r >> 1, pi = r & 1;
            int jj = u + (g >> 1) * 256, ab = g & 1;
            int base = half ? WLB_OFF : WLA_OFF;
            wbuf[base + (qq * 512 + jj) * 4 + pi * 2 + ab] = p.u;
        }
    }
}

// ---------------- fused encoder LSTMs: block 0 = stft (T=14), block 1 = wave (T=62) -------
__global__ __launch_bounds__(512, 2) __attribute__((amdgpu_waves_per_eu(2, 2)))
void lstm_enc5_kernel(const uint32_t* __restrict__ wS, const float* __restrict__ xpS,
                      float* __restrict__ shp, float* __restrict__ scp,
                      const uint32_t* __restrict__ wW, const float* __restrict__ xpW,
                      float* __restrict__ whp, float* __restrict__ wcp) {
    __shared__ uint4 wl_s[12 * 512];               // 96 KiB
    __shared__ __align__(16) uint32_t h_pk[2][128];
    const uint32_t* wbuf = blockIdx.x ? wW : wS;
    const float* xp = blockIdx.x ? xpW : xpS;
    float* h_out = blockIdx.x ? whp : shp;
    float* c_out = blockIdx.x ? wcp : scp;
    int T = blockIdx.x ? 62 : 14;
    int j = threadIdx.x;
    int u = j >> 1, kh = j & 1;
    const uint4* w4 = (const uint4*)wbuf;
    P13(DECLW4)
    P13(LOADW4)
    for (int i = j; i < 6144; i += 512) wl_s[i] = w4[WL4_OFF + i];
    if (j < 128) h_pk[0][j] = 0;
    float c = 0.f, h = 0.f;
    __syncthreads();
    int cur = 0;
    for (int t = 0; t < T; ++t) {
        const uint32_t* hp = &h_pk[cur][0];
        DOTS_ALL4()
        float s0 = a0 + b0, s1 = a1 + b1, s2 = a2 + b2, s3 = a3 + b3;
        const float* xr = xp + t * 1024;
        float zi = s0 + __shfl_xor(s0, 1) + xr[u];
        float zf = s1 + __shfl_xor(s1, 1) + xr[256 + u];
        float zg = s2 + __shfl_xor(s2, 1) + xr[512 + u];
        float zo = s3 + __shfl_xor(s3, 1) + xr[768 + u];
        c = sigmoidf_(zf) * c + sigmoidf_(zi) * tanhf_(zg);
        h = sigmoidf_(zo) * tanhf_(c);
        if (!kh) ((_Float16*)&h_pk[cur ^ 1][0])[u] = (_Float16)h;
        __syncthreads();
        cur ^= 1;
    }
    if (!kh) { h_out[u] = h; c_out[u] = c; }
}

// ---------------- decoder chain: dec6 structure + memo-SUFFIX recovery replay ----------------
// Key insight (this round): the memo is {a1 step, then a0 steps until convergence}. A
// truncated replay of M steps ends in state memo_st[M-1]; the next l's recovery is all-a0
// steps from that state — which is EXACTLY the memo's own suffix memo_st[M..memo_len-1],
// already materialized as uniq ids mid0+M..mid0+memo_len-1, ending at the converged state.
// So every recovery replays in O(1) from the first occurrence: no recovery builds at all.
// Gate: tk >= memo_len-M (a1 must not hit mid-recovery); else fall back to normal compute.
__global__ __launch_bounds__(512, 2) __attribute__((amdgpu_waves_per_eu(2, 2)))
void lstm_dec12_kernel(const uint32_t* __restrict__ wbuf, const float* __restrict__ a01,
                       const int* __restrict__ tok, const float* __restrict__ h0,
                       const float* __restrict__ c0, __hip_bfloat16* __restrict__ uniq,
                       uint32_t* __restrict__ rid, uint32_t* __restrict__ lrec,
                       int* __restrict__ gpar) {
    __shared__ uint4 wa_s[6 * 512];
    __shared__ uint4 wb_s[6 * 512];
    __shared__ __align__(16) uint32_t h_pk[2][128];
    __shared__ float zgo[256][2];
    __shared__ int flagv[2][4];
    __shared__ uint32_t memo_st[MEMO_T * 256];     // f16 h | f16 c per (memo step, u)
    __shared__ int tok_s[304];
    int j = threadIdx.x;
    int u = j & 255, hi = j >> 8;
    int colA = u + hi * 512, colB = colA + 256;
    const uint4* w4 = (const uint4*)wbuf;
    Q26(DECLW)
    Q26(LOADW)
    const uint4* srcA = (const uint4*)(wbuf + WLA_OFF);
    const uint4* srcB = (const uint4*)(wbuf + WLB_OFF);
    for (int i = j; i < 3072; i += 512) { wa_s[i] = srcA[i]; wb_s[i] = srcB[i]; }
    for (int i = j; i < 299; i += 512) tok_s[i] = tok[i];
    float a0A = a01[colA], a0B = a01[colB];
    float a1A = a01[1024 + colA], a1B = a01[1024 + colB];
    float h = 0.f, c = 0.f;
    if (!hi) {
        h = h0[u];
        c = c0[u];
        ((_Float16*)&h_pk[0][0])[u] = (_Float16)h;
    }
    __syncthreads();
    int cur = 0;
    bool prev_a0 = false, stat = false;
    bool memo_valid = false, building = false;
    int bidx = 0, memo_len = 0, mid0 = 0;
    int uc = 0, fpid = 0, step = 0, prk = -1;
#pragma unroll 1
    for (int l = 0; l < 299; ++l) {
        int tk = tok_s[l];
        // canonical l: full replay guaranteed, ends at the fixed point -> skip entirely
        if (stat && memo_valid && tk <= 128 - memo_len) {
            if (j == 0) lrec[l] = (uint32_t)fpid;
            step += 128;
            prev_a0 = true;
            prk = -1;
            continue;
        }
        if (j == 0) lrec[l] = LREC_NONE;
        int v = 0;
        // pending recovery (previous l ended with a truncated replay of length upk):
        // replay the memo SUFFIX memo_st[upk..memo_len-1] (ids mid0+upk..mid0+memo_len-1)
        int upk = prk;
        prk = -1;
        if (upk > 0 && upk < memo_len) {
            int n = memo_len - upk;
            if (tk >= n) {
                if (j < n) rid[step + j] = (uint32_t)(mid0 + upk + j);
                union { uint32_t w; _Float16 f[2]; } s;
                s.w = memo_st[(memo_len - 1) * 256 + u];
                h = (float)s.f[0];
                c = (float)s.f[1];
                if (!hi) ((_Float16*)&h_pk[cur][0])[u] = s.f[0];
                fpid = mid0 + memo_len - 1;
                stat = true;
                prev_a0 = true;
                step += n;
                v = n;
                __syncthreads();
            }
            // gate fail (tk < n): fall through — normal compute from the restored state
        }
        while (v < 128) {
            if (stat && v != tk) {
                // stationary under a0: rows == fixed-point row fpid; write ids only
                int nxt = (v < tk) ? tk : 128;
                int cnt = nxt - v;
                if (j < cnt) rid[step + j] = (uint32_t)fpid;
                step += cnt;
                v = nxt;
                continue;
            }
            if (v == tk && stat && memo_valid) {
                // replay memoized perturbation trajectory: ids only + state restore
                int M = (memo_len < 128 - v) ? memo_len : (128 - v);
                if (j < M) rid[step + j] = (uint32_t)(mid0 + j);
                if (!hi) {
                    union { uint32_t w; _Float16 f[2]; } s;
                    s.w = memo_st[(M - 1) * 256 + u];
                    h = (float)s.f[0];
                    c = (float)s.f[1];
                    ((_Float16*)&h_pk[cur][0])[u] = s.f[0];
                }
                step += M;
                v += M;
                if (M == memo_len) { stat = true; prev_a0 = true; }
                else { stat = false; prev_a0 = (M > 1); prk = M; }  // truncation -> suffix next l
                __syncthreads();
                continue;
            }
            // normal computed step (records memo during build)
            bool isa1 = (v == tk);
            if (isa1 && stat && !memo_valid && !building) { building = true; bidx = 0; mid0 = uc; }
            const uint32_t* hp = &h_pk[cur][0];
            DOTS_ALL()
            float zA = aA + (isa1 ? a1A : a0A);
            float zB = aB + (isa1 ? a1B : a0B);
            if (hi) { zgo[u][0] = zA; zgo[u][1] = zB; }
            __syncthreads();
            if (!hi) {
                float zg = zgo[u][0], zo = zgo[u][1];
                float cn = sigmoidf_(zB) * c + sigmoidf_(zA) * tanhf_(zg);
                float hn = sigmoidf_(zo) * tanhf_(cn);
                bool ok = (fabsf(hn - h) <= TOL) && (fabsf(cn - c) <= TOL) && !isa1 && prev_a0;
                unsigned long long bal = __ballot(ok ? 1 : 0);
                if ((j & 63) == 0) flagv[cur][j >> 6] = (bal == ~0ull) ? 1 : 0;
                h = hn;
                c = cn;
                unsigned short hb = bf16bits_(hn);
                ((unsigned short*)uniq)[(size_t)uc * 256 + u] = hb;
                if (u == 0) rid[step] = (uint32_t)uc;
                ((_Float16*)&h_pk[cur ^ 1][0])[u] = (_Float16)hn;
                if (building) {
                    union { uint32_t w; _Float16 f[2]; } s;
                    s.f[0] = (_Float16)hn;
                    s.f[1] = (_Float16)cn;
                    memo_st[bidx * 256 + u] = s.w;
                }
            }
            __syncthreads();
            stat = flagv[cur][0] && flagv[cur][1] && flagv[cur][2] && flagv[cur][3];
            cur ^= 1;
            prev_a0 = !isa1;
            fpid = uc;
            ++step;
            ++v;
            ++uc;
            if (building) {
                if (stat) { memo_len = bidx + 1; memo_valid = true; building = false; }
                else if (bidx + 1 >= MEMO_T) building = false;  // abort: too long
                else ++bidx;
            }
        }
        building = false;  // abort any memo build crossing an l boundary
    }
    if (j == 0) {
        gpar[0] = uc;                               // unique-row count
        gpar[1] = mid0;                             // memo base row id
        gpar[2] = memo_valid ? memo_len : 0;        // memo length (0 = no memo)
    }
}

// ---------------- tok extraction ----------------
__global__ void tok_kernel(const float* __restrict__ din, int* __restrict__ tok) {
    int l = blockIdx.x * 64 + threadIdx.x;
    if (l >= 299) return;
    int t = 0;
    for (int v = 0; v < 128; ++v)
        if (din[l * 128 + v] > 0.5f) t = v;
    tok[l] = t;
}

// ---------------- STFT conv1 (3x3x1->256) + relu + 2x2 maxpool ----------------
__global__ void stft_conv1_kernel(const float* __restrict__ in, const float* __restrict__ w,
                                  const float* __restrict__ b, float* __restrict__ out) {
    int c = threadIdx.x;
    int blk = blockIdx.x;
    int pw = blk % 255, ph = blk / 255;
    int h0 = 2 * ph, w0 = 2 * pw;
    float pin[4][4];
#pragma unroll
    for (int r = 0; r < 4; ++r)
#pragma unroll
        for (int s = 0; s < 4; ++s) pin[r][s] = in[(h0 + r) * 513 + (w0 + s)];
    float acc[2][2] = {};
#pragma unroll
    for (int dh = 0; dh < 3; ++dh)
#pragma unroll
        for (int dw = 0; dw < 3; ++dw) {
            float wv = w[(dh * 3 + dw) * 256 + c];
            acc[0][0] += pin[dh][dw] * wv;
            acc[0][1] += pin[dh][dw + 1] * wv;
            acc[1][0] += pin[dh + 1][dw] * wv;
            acc[1][1] += pin[dh + 1][dw + 1] * wv;
        }
    float m = fmaxf(fmaxf(acc[0][0], acc[0][1]), fmaxf(acc[1][0], acc[1][1]));
    out[(ph * 255 + pw) * 256 + c] = fmaxf(m + b[c], 0.f);
}

// ---------------- STFT conv2 (3x3x256->256) + relu + 2x2 maxpool, float4 LDS reads -------
__global__ void stft_conv2_kernel(const float* __restrict__ P1, const float* __restrict__ w,
                                  const float* __restrict__ b, float* __restrict__ out) {
    __shared__ __align__(16) float patch[4 * 8 * 256];
    int c = threadIdx.x;
    int blk = blockIdx.x;
    int pwg = blk % 42, ph = blk / 42;
    int pw0 = pwg * 3;
    int r0 = 2 * ph, c0 = 2 * pw0;
    for (int i = c; i < 4 * 8 * 256; i += 256) {
        int ci = i & 255;
        int t = i >> 8;
        int cc = t & 7, r = t >> 3;
        patch[i] = P1[((r0 + r) * 255 + (c0 + cc)) * 256 + ci];
    }
    __syncthreads();
    const float4* patch4 = (const float4*)patch;
    float acc[3][2][2] = {};
    for (int dh = 0; dh < 3; ++dh) {
        for (int ci = 0; ci < 256; ci += 4) {
            float4 p0[8], p1[8];
#pragma unroll
            for (int x = 0; x < 8; ++x) {
                p0[x] = patch4[((dh * 8 + x) * 256 + ci) >> 2];
                p1[x] = patch4[(((dh + 1) * 8 + x) * 256 + ci) >> 2];
            }
#pragma unroll
            for (int r = 0; r < 4; ++r) {
#pragma unroll
                for (int dw = 0; dw < 3; ++dw) {
                    float wv = w[((dh * 3 + dw) * 256 + ci + r) * 256 + c];
#pragma unroll
                    for (int o = 0; o < 3; ++o)
#pragma unroll
                        for (int s = 0; s < 2; ++s) {
                            int x = 2 * o + s + dw;
                            acc[o][0][s] += ((const float*)&p0[x])[r] * wv;
                            acc[o][1][s] += ((const float*)&p1[x])[r] * wv;
                        }
                }
            }
        }
    }
    float bv = b[c];
#pragma unroll
    for (int o = 0; o < 3; ++o) {
        float m = fmaxf(fmaxf(acc[o][0][0], acc[o][0][1]), fmaxf(acc[o][1][0], acc[o][1][1]));
        out[(ph * 126 + (pw0 + o)) * 256 + c] = fmaxf(m + bv, 0.f);
    }
}

// ---------------- STFT input projection: X[14,32256] @ Wi[32256,1024], split-K ------------
__global__ void xprojS_partial_kernel(const float* __restrict__ X, const float* __restrict__ Wi,
                                      float* __restrict__ part) {
    __shared__ __align__(16) float xbuf[14 * 504];
    int tid = threadIdx.x;
    int kc = blockIdx.x & 63;
    int cb = blockIdx.x >> 6;
    int col = cb * 256 + tid;
    int k0 = kc * 504;
    for (int i = tid; i < 14 * 504; i += 256) {
        int t = i / 504;
        int kk = i - t * 504;
        xbuf[i] = X[t * 32256 + k0 + kk];
    }
    __syncthreads();
    const float4* xb4 = (const float4*)xbuf;
    float acc[14] = {};
    for (int kk = 0; kk < 504; kk += 4) {
        float wv0 = Wi[(size_t)(k0 + kk) * 1024 + col];
        float wv1 = Wi[(size_t)(k0 + kk + 1) * 1024 + col];
        float wv2 = Wi[(size_t)(k0 + kk + 2) * 1024 + col];
        float wv3 = Wi[(size_t)(k0 + kk + 3) * 1024 + col];
#pragma unroll
        for (int t = 0; t < 14; ++t) {
            float4 xv = xb4[(t * 504 + kk) >> 2];
            acc[t] += xv.x * wv0 + xv.y * wv1 + xv.z * wv2 + xv.w * wv3;
        }
    }
#pragma unroll
    for (int t = 0; t < 14; ++t) part[(kc * 14 + t) * 1024 + col] = acc[t];
}

__global__ void xprojS_reduce_kernel(const float* __restrict__ part, const float* __restrict__ bias,
                                     float* __restrict__ xp) {
    int idx = blockIdx.x * 256 + threadIdx.x;  // < 14*1024
    int t = idx >> 10, col = idx & 1023;
    float s = bias[col];
    for (int kc = 0; kc < 64; ++kc) s += part[(kc * 14 + t) * 1024 + col];
    xp[idx] = s;
}

// ---------------- wave conv1 (k=3, 1024->256) + relu + pool2, float4 LDS reads ------------
__global__ void wave_conv1_kernel(const float* __restrict__ in, const float* __restrict__ w,
                                  const float* __restrict__ b, float* __restrict__ out) {
    __shared__ __align__(16) float patch[4 * 1024];
    int c = threadIdx.x, t = blockIdx.x;
    for (int i = c; i < 4 * 1024; i += 256) patch[i] = in[(2 * t) * 1024 + i];
    __syncthreads();
    const float4* patch4 = (const float4*)patch;
    float acc0 = 0.f, acc1 = 0.f;
    for (int dt = 0; dt < 3; ++dt)
        for (int ci = 0; ci < 1024; ci += 4) {
            float4 q0 = patch4[(dt * 1024 + ci) >> 2];
            float4 q1 = patch4[((dt + 1) * 1024 + ci) >> 2];
#pragma unroll
            for (int r = 0; r < 4; ++r) {
                float wv = w[(dt * 1024 + ci + r) * 256 + c];
                acc0 += ((const float*)&q0)[r] * wv;
                acc1 += ((const float*)&q1)[r] * wv;
            }
        }
    out[t * 256 + c] = fmaxf(fmaxf(acc0, acc1) + b[c], 0.f);
}

// ---------------- wave conv2 (k=3, 256->256) + relu + pool2, float4 LDS reads -------------
__global__ void wave_conv2_kernel(const float* __restrict__ in, const float* __restrict__ w,
                                  const float* __restrict__ b, float* __restrict__ out) {
    __shared__ __align__(16) float patch[4 * 256];
    int c = threadIdx.x, t = blockIdx.x;
    for (int i = c; i < 4 * 256; i += 256) patch[i] = in[(2 * t) * 256 + i];
    __syncthreads();
    const float4* patch4 = (const float4*)patch;
    float acc0 = 0.f, acc1 = 0.f;
    for (int dt = 0; dt < 3; ++dt)
        for (int ci = 0; ci < 256; ci += 4) {
            float4 q0 = patch4[(dt * 256 + ci) >> 2];
            float4 q1 = patch4[((dt + 1) * 256 + ci) >> 2];
#pragma unroll
            for (int r = 0; r < 4; ++r) {
                float wv = w[(dt * 256 + ci + r) * 256 + c];
                acc0 += ((const float*)&q0)[r] * wv;
                acc1 += ((const float*)&q1)[r] * wv;
            }
        }
    out[t * 256 + c] = fmaxf(fmaxf(acc0, acc1) + b[c], 0.f);
}

// ---------------- wave input projection X[62,256] @ Wi[256,1024] + b ----------------
__global__ void xprojW_kernel(const float* __restrict__ X, const float* __restrict__ Wi,
                              const float* __restrict__ bias, float* __restrict__ xp) {
    int idx = blockIdx.x * 256 + threadIdx.x;  // 62*1024
    int t = idx >> 10, col = idx & 1023;
    float s = bias[col];
    for (int k = 0; k < 256; ++k) s += X[t * 256 + k] * Wi[k * 1024 + col];
    xp[idx] = s;
}

// ---------------- state reducers ----------------
__global__ void reduce_state_kernel(const float* __restrict__ sh, const float* __restrict__ sc,
                                    const float* __restrict__ wh, const float* __restrict__ wc,
                                    const float* __restrict__ rhw, const float* __restrict__ rhb,
                                    const float* __restrict__ rcw, const float* __restrict__ rcb,
                                    float* __restrict__ h0, float* __restrict__ c0) {
    int m = threadIdx.x;  // 256
    float ah = rhb[m], ac = rcb[m];
    for (int k = 0; k < 256; ++k) {
        ah += sh[k] * rhw[k * 256 + m];
        ac += sc[k] * rcw[k * 256 + m];
    }
    for (int k = 0; k < 256; ++k) {
        ah += wh[k] * rhw[(256 + k) * 256 + m];
        ac += wc[k] * rcw[(256 + k) * 256 + m];
    }
    h0[m] = ah;
    c0[m] = ac;
}

// ---------------- a0/a1 = emb[s] @ d_Wi + d_b ----------------
__global__ void a01_kernel(const float* __restrict__ emb, const float* __restrict__ Wi,
                           const float* __restrict__ bias, float* __restrict__ a01) {
    int idx = blockIdx.x * 256 + threadIdx.x;  // 2048
    int s = idx >> 10, j = idx & 1023;
    float acc = bias[j];
    for (int k = 0; k < 256; ++k) acc += emb[s * 256 + k] * Wi[k * 1024 + j];
    a01[idx] = acc;
}

// ---------------- projection + softmax over UNIQUE rows: 4 rows/block ----------------
__global__ __launch_bounds__(256) void proj_softmax_kernel(const __hip_bfloat16* __restrict__ uniq,
                                                           const float* __restrict__ Wo,
                                                           const float* __restrict__ bo,
                                                           const int* __restrict__ gpar,
                                                           float* __restrict__ ptab) {
    __shared__ float hrows[4][256];
    __shared__ float llds[4][128];
    int tid = threadIdx.x;
    int rbase = blockIdx.x * 4;
    int U = gpar[0];
    if (rbase >= U) return;   // early-exit: only ~uc/4 blocks do work
    for (int i = tid; i < 1024; i += 256)
        hrows[i >> 8][i & 255] = __bfloat162float(uniq[(size_t)rbase * 256 + i]);
    __syncthreads();
    int w = tid & 127, half = tid >> 7;
    int k0 = half * 128;
    float acc[4] = {};
    for (int k = 0; k < 128; ++k) {
        float wv = Wo[(k0 + k) * 128 + w];
#pragma unroll
        for (int r = 0; r < 4; ++r) acc[r] += hrows[r][k0 + k] * wv;
    }
    if (half == 0) {
#pragma unroll
        for (int r = 0; r < 4; ++r) llds[r][w] = acc[r] + bo[w];
    }
    __syncthreads();
    if (half == 1) {
#pragma unroll
        for (int r = 0; r < 4; ++r) llds[r][w] += acc[r];
    }
    __syncthreads();
    int rr = tid >> 6, lane = tid & 63;
    float x0 = llds[rr][lane], x1 = llds[rr][lane + 64];
    float mx = fmaxf(x0, x1);
    for (int off = 32; off > 0; off >>= 1) mx = fmaxf(mx, __shfl_xor(mx, off));
    float e0 = __expf(x0 - mx), e1 = __expf(x1 - mx);
    float sm = e0 + e1;
    for (int off = 32; off > 0; off >>= 1) sm += __shfl_xor(sm, off);
    float inv = 1.f / sm;
    int row = rbase + rr;
    float* op = ptab + (size_t)row * 128;
    op[lane] = e0 * inv;
    op[lane + 64] = e1 * inv;
}

// ---------------- scatter: out[v,l,:] = ptab[id(l,v)]  (l==299 -> 0) ----------------
__global__ void scatter_out_kernel(const float* __restrict__ ptab,
                                   const uint32_t* __restrict__ rid,
                                   const uint32_t* __restrict__ lrec,
                                   const int* __restrict__ gpar,
                                   const int* __restrict__ tok,
                                   float* __restrict__ out) {
    int idx = blockIdx.x * 256 + threadIdx.x;  // 300*128*128 = 4915200
    int w = idx & 127;
    int step = idx >> 7;       // l*128 + v, l in [0,300)
    int l = step >> 7;
    int v = step & 127;
    float val = 0.f;
    if (l < 299) {
        uint32_t fr = lrec[l];
        uint32_t id;
        if (fr == LREC_NONE) {
            id = rid[step];
        } else {
            int tk = tok[l];
            int d = v - tk;
            int mlen = gpar[2];
            id = (d >= 0 && d < mlen) ? (uint32_t)(gpar[1] + d) : fr;
        }
        val = ptab[(size_t)id * 128 + w];
    }
    out[((size_t)v * 300 + l) * 128 + w] = val;
}

extern "C" void kernel_launch(void* const* d_in, const int* in_sizes, int n_in, void* d_out,
                              int out_size, void* d_ws, size_t ws_size, hipStream_t stream) {
    const float* stft = (const float*)d_in[0];
    const float* wave = (const float*)d_in[1];
    const float* din = (const float*)d_in[2];
    const float* s_cw1 = (const float*)d_in[3];
    const float* s_cb1 = (const float*)d_in[4];
    const float* s_cw2 = (const float*)d_in[5];
    const float* s_cb2 = (const float*)d_in[6];
    const float* s_Wi = (const float*)d_in[7];
    const float* s_Wh = (const float*)d_in[8];
    const float* s_b = (const float*)d_in[9];
    const float* w_cw1 = (const float*)d_in[10];
    const float* w_cb1 = (const float*)d_in[11];
    const float* w_cw2 = (const float*)d_in[12];
    const float* w_cb2 = (const float*)d_in[13];
    const float* w_Wi = (const float*)d_in[14];
    const float* w_Wh = (const float*)d_in[15];
    const float* w_b = (const float*)d_in[16];
    const float* rh_w = (const float*)d_in[17];
    const float* rh_b = (const float*)d_in[18];
    const float* rc_w = (const float*)d_in[19];
    const float* rc_b = (const float*)d_in[20];
    const float* emb = (const float*)d_in[21];
    const float* d_Wi = (const float*)d_in[22];
    const float* d_Wh = (const float*)d_in[23];
    const float* d_b = (const float*)d_in[24];
    const float* out_w = (const float*)d_in[25];
    const float* out_b = (const float*)d_in[26];
    float* out = (float*)d_out;
    float* ws = (float*)d_ws;

    // workspace layout (float offsets)
    const size_t off_P1s = 0;                         // 31*255*256 = 2023680 (reused for packed weights)
    const size_t off_P2s = off_P1s + 2023680;         // 14*126*256 = 451584
    const size_t off_partS = off_P2s + 451584;        // 64*14*1024 = 917504
    const size_t off_P1w = off_partS + 917504;        // 127*256 = 32512
    const size_t off_P2w = off_P1w + 32512;           // 62*256 = 15872
    const size_t off_xprojS = off_P2w + 15872;        // 14*1024
    const size_t off_xprojW = off_xprojS + 14336;     // 62*1024
    const size_t off_sh = off_xprojW + 63488;         // 4*256 states
    const size_t off_sc = off_sh + 256;
    const size_t off_wh = off_sc + 256;
    const size_t off_wc = off_wh + 256;
    const size_t off_h0 = off_wc + 256;
    const size_t off_c0 = off_h0 + 256;
    const size_t off_a01 = off_c0 + 256;              // 2048
    const size_t off_tok = off_a01 + 2048;            // 299 ints (512 slots)
    const size_t off_uniq = off_tok + 512;            // bf16 region: 38272*256 bf16 = 4898816 floats
    const size_t off_rid = off_uniq + 4898816;        // 38272 u32
    const size_t off_lrec = off_rid + 38272;          // 300 u32 (padded 320)
    const size_t off_gpar = off_lrec + 320;           // 3 ints (padded 64)
    const size_t off_ptab = off_gpar + 64;            // 38272*128 floats (worst-case unique rows)
    __hip_bfloat16* h_uniq = (__hip_bfloat16*)(ws + off_uniq);
    uint32_t* rid = (uint32_t*)(ws + off_rid);
    uint32_t* lrec = (uint32_t*)(ws + off_lrec);
    int* gpar = (int*)(ws + off_gpar);
    float* ptab = ws + off_ptab;
    int* tok = (int*)(ws + off_tok);
    // packed f16 weights overlay the P1s region (free after stft_conv2): 3 x 131072 dwords
    uint32_t* wrS = (uint32_t*)(ws + off_P1s);
    uint32_t* wrW = wrS + 131072;
    uint32_t* wrD = wrW + 131072;

    tok_kernel<<<5, 64, 0, stream>>>(din, tok);

    // STFT conv pipeline (P1s in use until stft_conv2 completes)
    stft_conv1_kernel<<<31 * 255, 256, 0, stream>>>(stft, s_cw1, s_cb1, ws + off_P1s);
    stft_conv2_kernel<<<14 * 42, 256, 0, stream>>>(ws + off_P1s, s_cw2, s_cb2, ws + off_P2s);

    // repack all three Wh matrices (P1s region now free) — one fused launch
    prep_wh_kernel<<<1536, 256, 0, stream>>>(s_Wh, w_Wh, d_Wh, wrS, wrW, wrD);

    // waveform branch convs
    wave_conv1_kernel<<<127, 256, 0, stream>>>(wave, w_cw1, w_cb1, ws + off_P1w);
    wave_conv2_kernel<<<62, 256, 0, stream>>>(ws + off_P1w, w_cw2, w_cb2, ws + off_P2w);

    // input projections
    xprojS_partial_kernel<<<256, 256, 0, stream>>>(ws + off_P2s, s_Wi, ws + off_partS);
    xprojS_reduce_kernel<<<56, 256, 0, stream>>>(ws + off_partS, s_b, ws + off_xprojS);
    xprojW_kernel<<<248, 256, 0, stream>>>(ws + off_P2w, w_Wi, w_b, ws + off_xprojW);

    // both encoder LSTMs concurrently (2 blocks on 2 CUs)
    lstm_enc5_kernel<<<2, 512, 0, stream>>>(wrS, ws + off_xprojS, ws + off_sh, ws + off_sc,
                                            wrW, ws + off_xprojW, ws + off_wh, ws + off_wc);

    // reducers + decoder precompute
    reduce_state_kernel<<<1, 256, 0, stream>>>(ws + off_sh, ws + off_sc, ws + off_wh, ws + off_wc,
                                               rh_w, rh_b, rc_w, rc_b, ws + off_h0, ws + off_c0);
    a01_kernel<<<8, 256, 0, stream>>>(emb, d_Wi, d_b, ws + off_a01);

    // sequential decoder chain (critical path) — memo-suffix recovery replay
    lstm_dec12_kernel<<<1, 512, 0, stream>>>(wrD, ws + off_a01, tok, ws + off_h0, ws + off_c0,
                                             h_uniq, rid, lrec, gpar);

    // parallel epilogue: project unique rows only, then scatter to output
    proj_softmax_kernel<<<NSTEP / 4, 256, 0, stream>>>(h_uniq, out_w, out_b, gpar, ptab);
    scatter_out_kernel<<<19200, 256, 0, stream>>>(ptab, rid, lrec, gpar, tok, out);
}